// Round 1
// baseline (21425.896 us; speedup 1.0000x reference)
//
#include <hip/hip_runtime.h>
#include <math.h>

#define SPAT 196608   // 64*64*48
#define EPSV 1e-5f

__device__ __forceinline__ float geluf(float x){
    return 0.5f*x*(1.0f + erff(x*0.70710678118654752440f));
}
__device__ __forceinline__ float wred(float v){
    #pragma unroll
    for(int o=32;o>0;o>>=1) v += __shfl_down(v,o);
    return v;
}

// ---------------- twiddle tables ----------------
// tab layout (floats):
// 0:    cz  [z*8+k]    384   (passD z-inverse)
// 384:  sz  [z*8+k]    384
// 768:  czT [k*48+z]   384   (passA forward z-DFT)
// 1152: szT [k*48+z]   384
// 1536: cxy [y*16+ki]  1024  (fused inverse)
// 2560: sxy [y*16+ki]  1024
// 3584: cxyT[ki*64+y]  1024  (passB / passC forward)
// 4608: sxyT[ki*64+y]  1024
__global__ void k_tables(float* tab){
    for(int idx=threadIdx.x; idx<384; idx+=blockDim.x){
        int z = idx>>3, k = idx&7;
        double a = 6.283185307179586476925286766559 * (double)((k*z)%48) / 48.0;
        float c = (float)cos(a), s = (float)sin(a);
        tab[idx]=c; tab[384+idx]=s;
        tab[768 + k*48+z]=c; tab[1152 + k*48+z]=s;
    }
    for(int idx=threadIdx.x; idx<1024; idx+=blockDim.x){
        int y = idx>>4, ki = idx&15;
        int ka = ki<8 ? ki : ki+48;
        double a = 6.283185307179586476925286766559 * (double)((ka*y)%64) / 64.0;
        float c=(float)cos(a), s=(float)sin(a);
        tab[1536+idx]=c; tab[2560+idx]=s;
        tab[3584 + ki*64+y]=c; tab[4608 + ki*64+y]=s;
    }
}

// ---------------- lifting + initial stats ----------------
__global__ void k_lift(const float* __restrict__ x, const float* __restrict__ pw,
                       const float* __restrict__ pb, float* __restrict__ h,
                       float* __restrict__ stats){
    __shared__ float inl[1920];
    __shared__ float outl[3840];
    __shared__ float wl[1040];
    __shared__ float bl[80];
    int b = blockIdx.x >> 12; int xy = blockIdx.x & 4095;
    const float* xp = x + ((size_t)(b*4096 + xy))*1920;
    for(int li=threadIdx.x; li<1920; li+=blockDim.x) inl[li] = xp[li];
    for(int li=threadIdx.x; li<1040; li+=blockDim.x) wl[li] = pw[li];
    for(int li=threadIdx.x; li<80;   li+=blockDim.x) bl[li] = pb[li];
    __syncthreads();
    float gx = (float)(xy>>6) * (1.0f/63.0f);
    float gy = (float)(xy&63) * (1.0f/63.0f);
    for(int oi=threadIdx.x; oi<3840; oi+=blockDim.x){
        int g = oi/960; int c = (oi/48)%20; int z = oi%48;
        const float* w = wl + g*260;
        float acc = bl[g*20+c];
        const float* iv = inl + z*40 + g*10;
        #pragma unroll
        for(int j=0;j<10;j++) acc += iv[j]*w[j*20+c];
        acc += gx*w[200+c] + gy*w[220+c] + ((float)z*(1.0f/47.0f))*w[240+c];
        outl[(g*20+c)*48+z] = acc;
        h[((size_t)(b*80 + g*20+c))*SPAT + xy*48 + z] = acc;
    }
    __syncthreads();
    int wid = threadIdx.x>>6, lane = threadIdx.x&63;
    for(int ch=wid; ch<80; ch+=4){
        float v = lane<48 ? outl[ch*48+lane] : 0.0f;
        float s1 = wred(v), s2 = wred(v*v);
        if(lane==0){ atomicAdd(&stats[(b*80+ch)*2], s1); atomicAdd(&stats[(b*80+ch)*2+1], s2); }
    }
}

// ---------------- pass A: gather + z-DFT + residual conv ----------------
__global__ void k_passA(const float* __restrict__ h, const float* __restrict__ ww,
                        const float* __restrict__ wb, float* __restrict__ rbuf,
                        float* __restrict__ zbuf, const float* __restrict__ tab,
                        int li, int g0, int g1, int g2){
    __shared__ __align__(16) float vl[2880];   // 60ch x 48z
    __shared__ float wl[1600];
    __shared__ float wsum[400];
    __shared__ float wbl[20];
    __shared__ __align__(16) float czl[384], szl[384];  // [k][z]
    int b = blockIdx.x >> 12; int xy = blockIdx.x & 4095;
    int dgx[3] = {g0,g1,g2};
    for(int t=threadIdx.x; t<2880; t+=blockDim.x){
        int d = t/48, z = t - d*48;
        int ch = dgx[d/20]*20 + d%20;
        vl[t] = h[((size_t)(b*80+ch))*SPAT + xy*48 + z];
    }
    for(int t=threadIdx.x; t<1600; t+=blockDim.x) wl[t] = ww[li*1600 + t];
    for(int t=threadIdx.x; t<20;   t+=blockDim.x) wbl[t] = wb[li*20 + t];
    for(int t=threadIdx.x; t<384;  t+=blockDim.x){ czl[t]=tab[768+t]; szl[t]=tab[1152+t]; }
    __syncthreads();
    for(int t=threadIdx.x; t<400; t+=blockDim.x){
        int o = t/20, c = t%20;
        wsum[t] = wl[o*80+c] + wl[o*80+20+c];
    }
    __syncthreads();
    if(threadIdx.x < 240){
        // z-DFT: (d-pair, k)
        int dp = threadIdx.x>>3, k = threadIdx.x&7;
        int d0 = dp*2;
        const float4* va = (const float4*)(vl + d0*48);
        const float4* vb = (const float4*)(vl + d0*48+48);
        const float4* tc = (const float4*)(czl + k*48);
        const float4* tsv= (const float4*)(szl + k*48);
        float r0=0,i0=0,r1=0,i1=0;
        #pragma unroll
        for(int z4=0;z4<12;z4++){
            float4 c = tc[z4], s = tsv[z4], a = va[z4], e = vb[z4];
            r0 += a.x*c.x + a.y*c.y + a.z*c.z + a.w*c.w;
            i0 -= a.x*s.x + a.y*s.y + a.z*s.z + a.w*s.w;
            r1 += e.x*c.x + e.y*c.y + e.z*c.z + e.w*c.w;
            i1 -= e.x*s.x + e.y*s.y + e.z*s.z + e.w*s.w;
        }
        size_t i0x = (((size_t)(b*60+d0)*4096 + xy)*8 + k)*2;
        size_t i1x = (((size_t)(b*60+d0+1)*4096 + xy)*8 + k)*2;
        zbuf[i0x]=r0; zbuf[i0x+1]=i0; zbuf[i1x]=r1; zbuf[i1x+1]=i1;
        // residual: o x z-quads
        int o = threadIdx.x/12, zq = threadIdx.x%12;
        int z0 = zq*4;
        float4 acc = {wbl[o],wbl[o],wbl[o],wbl[o]};
        #pragma unroll
        for(int c=0;c<20;c++){
            float wv = wsum[o*20+c];
            float4 v = *(const float4*)(vl + c*48 + z0);
            acc.x += wv*v.x; acc.y += wv*v.y; acc.z += wv*v.z; acc.w += wv*v.w;
        }
        #pragma unroll
        for(int c=0;c<20;c++){
            float wv = wl[o*80+40+c];
            float4 v = *(const float4*)(vl + (20+c)*48 + z0);
            acc.x += wv*v.x; acc.y += wv*v.y; acc.z += wv*v.z; acc.w += wv*v.w;
        }
        #pragma unroll
        for(int c=0;c<20;c++){
            float wv = wl[o*80+60+c];
            float4 v = *(const float4*)(vl + (40+c)*48 + z0);
            acc.x += wv*v.x; acc.y += wv*v.y; acc.z += wv*v.z; acc.w += wv*v.w;
        }
        float* rp = rbuf + ((size_t)(b*20+o))*SPAT + xy*48 + z0;
        rp[0]=acc.x; rp[1]=acc.y; rp[2]=acc.z; rp[3]=acc.w;
    }
}

// ---------------- pass B: forward y-DFT (64y -> 16ky) ----------------
__global__ void k_passB(const float* __restrict__ zbuf, float* __restrict__ ybuf,
                        const float* __restrict__ tab){
    __shared__ __align__(16) float zl[1024];
    __shared__ __align__(16) float cl[1024], sl[1024];
    int blk = blockIdx.x;
    int x = blk & 63; int d = (blk/64)%60; int b = blk/3840;
    const float* src = zbuf + ((size_t)(b*60+d)*4096 + x*64)*16;
    for(int t=threadIdx.x;t<1024;t+=blockDim.x) zl[t]=src[t];
    for(int t=threadIdx.x;t<1024;t+=blockDim.x){ cl[t]=tab[3584+t]; sl[t]=tab[4608+t]; }
    __syncthreads();
    int kyi = threadIdx.x>>3, kz = threadIdx.x&7;
    float fr=0, fi=0;
    const float2* tc = (const float2*)(cl + kyi*64);
    const float2* ts = (const float2*)(sl + kyi*64);
    for(int y2=0;y2<32;y2++){
        float2 c2 = tc[y2], s2 = ts[y2];
        float2 v0 = *(const float2*)(zl + ((2*y2)*8+kz)*2);
        float2 v1 = *(const float2*)(zl + ((2*y2+1)*8+kz)*2);
        fr += v0.x*c2.x + v0.y*s2.x + v1.x*c2.y + v1.y*s2.y;
        fi += v0.y*c2.x - v0.x*s2.x + v1.y*c2.y - v1.x*s2.y;
    }
    size_t idx = ((((size_t)(b*60+d)*64 + x)*16 + kyi)*8 + kz)*2;
    ybuf[idx]=fr; ybuf[idx+1]=fi;
}

// ---------------- pass C: forward x-DFT + instance-norm-1 fold ----------------
__global__ void k_passC(const float* __restrict__ ybuf, float* __restrict__ fbuf,
                        const float* __restrict__ stats, const float* __restrict__ tab,
                        int g0,int g1,int g2){
    __shared__ __align__(16) float yl[1024];   // [kz][x][2]
    __shared__ __align__(16) float cl[1024], sl[1024];
    int blk = blockIdx.x;
    int kyi = blk & 15; int d = (blk/16)%60; int b = blk/960;
    for(int t=threadIdx.x;t<1024;t+=blockDim.x){
        int xx = t>>4; int r = t&15;  // r = kz*2+ri
        float v = ybuf[((((size_t)(b*60+d)*64 + xx)*16 + kyi)*8)*2 + r];
        yl[(r>>1)*128 + xx*2 + (r&1)] = v;
    }
    for(int t=threadIdx.x;t<1024;t+=blockDim.x){ cl[t]=tab[3584+t]; sl[t]=tab[4608+t]; }
    __syncthreads();
    int dgx[3]={g0,g1,g2};
    int ch = dgx[d/20]*20 + d%20;
    float s1 = stats[(b*80+ch)*2], s2 = stats[(b*80+ch)*2+1];
    float mean = s1*(1.0f/196608.0f);
    float var = s2*(1.0f/196608.0f) - mean*mean;
    float sc = rsqrtf(var + EPSV);
    int kxi = threadIdx.x>>3, kz = threadIdx.x&7;
    float fr=0, fi=0;
    const float2* tc = (const float2*)(cl + kxi*64);
    const float2* ts = (const float2*)(sl + kxi*64);
    const float2* vz = (const float2*)(yl + kz*128);
    for(int x2=0;x2<32;x2++){
        float2 c2 = tc[x2], s2v = ts[x2];
        float2 v0 = vz[2*x2], v1 = vz[2*x2+1];
        fr += v0.x*c2.x + v0.y*s2v.x + v1.x*c2.y + v1.y*s2v.y;
        fi += v0.y*c2.x - v0.x*s2v.x + v1.y*c2.y - v1.x*s2v.y;
    }
    fr *= sc; fi *= sc;
    if(kxi==0 && kyi==0 && kz==0){ fr=0.0f; fi=0.0f; }
    size_t idx = ((((size_t)(b*60+d)*16 + kxi)*16 + kyi)*8 + kz)*2;
    fbuf[idx]=fr; fbuf[idx+1]=fi;
}

// ---------------- spectral multiply (+ stat zeroing for this iter) ----------------
__global__ void k_spec(const float* __restrict__ fbuf, const float* __restrict__ sw,
                       float* __restrict__ gbuf, float* __restrict__ stats,
                       float* __restrict__ stat2, int li, int grp){
    int blk = blockIdx.x;
    int m1p = blk & 3, o = (blk>>2)%20, q = blk/80;
    if(q==0 && m1p==0 && threadIdx.x<2){
        int b = threadIdx.x;
        stat2[(b*20+o)*2]=0.f; stat2[(b*20+o)*2+1]=0.f;
        stats[(b*80+grp*20+o)*2]=0.f; stats[(b*80+grp*20+o)*2+1]=0.f;
    }
    int offx = (q&1)*8, offy = (q>>1)*8;
    int t = threadIdx.x;
    int m1 = m1p*2 + (t>>5);
    int m2 = (t>>2)&7;
    int m3 = (t&3)*2;
    int tw = m1*64 + m2*8 + m3;
    int kxi = m1+offx, kyi = m2+offy;
    int fo = (kxi*16 + kyi)*8 + m3;
    const float4* wp  = (const float4*)(sw + ((size_t)((li*4+q)*1600) + o)*1024 + (size_t)tw*2);
    const float4* f00 = (const float4*)(fbuf + (size_t)fo*2);
    float r00=0,i00=0,r01=0,i01=0, r10=0,i10=0,r11=0,i11=0;
    #pragma unroll 4
    for(int c=0;c<20;c++){
        float4 wa = wp[(size_t)c*5120];
        float4 wb4= wp[(size_t)(c+20)*5120];
        float wr0 = wa.x + wb4.x, wi0 = wa.y + wb4.y, wr1 = wa.z + wb4.z, wi1 = wa.w + wb4.w;
        float4 f0 = f00[(size_t)c*1024];
        float4 f1 = f00[(size_t)(60+c)*1024];
        r00 += f0.x*wr0 - f0.y*wi0; i00 += f0.x*wi0 + f0.y*wr0;
        r01 += f0.z*wr1 - f0.w*wi1; i01 += f0.z*wi1 + f0.w*wr1;
        r10 += f1.x*wr0 - f1.y*wi0; i10 += f1.x*wi0 + f1.y*wr0;
        r11 += f1.z*wr1 - f1.w*wi1; i11 += f1.z*wi1 + f1.w*wr1;
    }
    #pragma unroll 4
    for(int c=0;c<40;c++){
        float4 wa = wp[(size_t)(c+40)*5120];
        float4 f0 = f00[(size_t)(20+c)*1024];
        float4 f1 = f00[(size_t)(80+c)*1024];
        r00 += f0.x*wa.x - f0.y*wa.y; i00 += f0.x*wa.y + f0.y*wa.x;
        r01 += f0.z*wa.z - f0.w*wa.w; i01 += f0.z*wa.w + f0.w*wa.z;
        r10 += f1.x*wa.x - f1.y*wa.y; i10 += f1.x*wa.y + f1.y*wa.x;
        r11 += f1.z*wa.z - f1.w*wa.w; i11 += f1.z*wa.w + f1.w*wa.z;
    }
    float4* g0 = (float4*)(gbuf + (size_t)o*4096 + fo*2);
    float4* g1 = (float4*)(gbuf + (size_t)(20+o)*4096 + fo*2);
    *g0 = make_float4(r00,i00,r01,i01);
    *g1 = make_float4(r10,i10,r11,i11);
}

// ---------------- fused inverse x + y (+ Parseval stats for norm2) ----------------
__global__ void k_inv(const float* __restrict__ gbuf, float* __restrict__ iybuf,
                      float* __restrict__ stat2, const float* __restrict__ tab){
    __shared__ float gl[4096];
    __shared__ float tmp[256];
    __shared__ float cl[1024], sl[1024];
    int blk = blockIdx.x;
    int nx = blk&63, o = (blk>>6)%20, b = blk/1280;
    const float* src = gbuf + (size_t)(b*20+o)*4096;
    for(int t=threadIdx.x;t<4096;t+=blockDim.x) gl[t]=src[t];
    for(int t=threadIdx.x;t<1024;t+=blockDim.x){ cl[t]=tab[1536+t]; sl[t]=tab[2560+t]; }
    __syncthreads();
    {
        int kyi = threadIdx.x>>3, kz = threadIdx.x&7;
        float ar=0, ai=0;
        #pragma unroll 4
        for(int kxi=0;kxi<16;kxi++){
            float gr = gl[((kxi*16+kyi)*8+kz)*2], gi2 = gl[((kxi*16+kyi)*8+kz)*2+1];
            float c = cl[nx*16+kxi], s = sl[nx*16+kxi];
            ar += gr*c - gi2*s;
            ai += gi2*c + gr*s;
        }
        tmp[threadIdx.x*2]   = ar*(1.0f/64.0f);
        tmp[threadIdx.x*2+1] = ai*(1.0f/64.0f);
    }
    __syncthreads();
    float p1=0,p2=0;
    for(int j=0;j<4;j++){
        int out = threadIdx.x + j*128;
        int ny = out>>3, kz = out&7;
        float ar=0, ai=0;
        #pragma unroll 4
        for(int kyi=0;kyi<16;kyi++){
            float vr = tmp[(kyi*8+kz)*2], vi = tmp[(kyi*8+kz)*2+1];
            float c = cl[ny*16+kyi], s = sl[ny*16+kyi];
            ar += vr*c - vi*s;
            ai += vi*c + vr*s;
        }
        ar *= (1.0f/64.0f); ai *= (1.0f/64.0f);
        size_t idx = ((((size_t)(b*20+o)*64+nx)*64+ny)*8+kz)*2;
        iybuf[idx]=ar; iybuf[idx+1]=ai;
        if(kz==0){ p1 += ar; p2 += ar*ar; }
        else p2 += 2.0f*(ar*ar+ai*ai);
    }
    p2 *= (1.0f/48.0f);
    float r1=wred(p1), r2=wred(p2);
    if((threadIdx.x&63)==0){ atomicAdd(&stat2[(b*20+o)*2], r1); atomicAdd(&stat2[(b*20+o)*2+1], r2); }
}

// ---------------- pass D: z-inverse + norm2 + MLP + residual add + h write + stats ----------------
__global__ void __launch_bounds__(256) k_passD(
        const float* __restrict__ iybuf, const float* __restrict__ rbuf,
        const float* __restrict__ w1, const float* __restrict__ b1,
        const float* __restrict__ w2, const float* __restrict__ b2,
        float* __restrict__ h, float* __restrict__ stats,
        const float* __restrict__ stat2, const float* __restrict__ tab,
        int li, int grp){
    __shared__ float dl[2560];
    __shared__ float vl[7680];
    __shared__ float w1l[400], w2l[400], b1l[20], b2l[20], m2l[20], s2l[20];
    __shared__ float czl[384], szl[384];
    int blk = blockIdx.x;
    int nyt = blk&7, nx=(blk>>3)&63, b = blk>>9;
    for(int t=threadIdx.x;t<2560;t+=blockDim.x){
        int o = t>>7, j = t&127;
        dl[t] = iybuf[((((size_t)(b*20+o)*64+nx)*64 + nyt*8)*8)*2 + j];
    }
    for(int t=threadIdx.x;t<400;t+=blockDim.x){ w1l[t]=w1[li*400+t]; w2l[t]=w2[li*400+t]; }
    if(threadIdx.x<20){
        int t = threadIdx.x;
        b1l[t]=b1[li*20+t]; b2l[t]=b2[li*20+t];
        float S1 = stat2[(b*20+t)*2], S2 = stat2[(b*20+t)*2+1];
        float mean = S1*(1.0f/196608.0f);
        float var = S2*(1.0f/196608.0f) - mean*mean;
        m2l[t]=mean; s2l[t]=rsqrtf(var+EPSV);
    }
    for(int t=threadIdx.x;t<384;t+=blockDim.x){ czl[t]=tab[t]; szl[t]=tab[384+t]; }
    __syncthreads();
    for(int idx=threadIdx.x; idx<7680; idx+=blockDim.x){
        int o = idx/384, p = idx%384;
        int ny = p/48, nz = p%48;
        const float* dd = dl + o*128 + ny*16;
        float acc = dd[0];
        #pragma unroll
        for(int k=1;k<8;k++)
            acc += 2.0f*(dd[k*2]*czl[nz*8+k] - dd[k*2+1]*szl[nz*8+k]);
        float xv = acc*(1.0f/48.0f);
        vl[o*384+p] = (xv - m2l[o])*s2l[o];
    }
    __syncthreads();
    for(int p=threadIdx.x; p<384; p+=blockDim.x){
        float vj[20], t1[20];
        #pragma unroll
        for(int j2=0;j2<20;j2++) vj[j2]=vl[j2*384+p];
        #pragma unroll
        for(int oo=0;oo<20;oo++){
            float a = b1l[oo];
            #pragma unroll
            for(int j2=0;j2<20;j2++) a += vj[j2]*w1l[oo*20+j2];
            t1[oo] = geluf(a);
        }
        #pragma unroll
        for(int oo=0;oo<20;oo++){
            float a = b2l[oo];
            #pragma unroll
            for(int j2=0;j2<20;j2++) a += t1[j2]*w2l[oo*20+j2];
            vl[oo*384+p] = a;
        }
    }
    __syncthreads();
    int sb = (nx*64 + nyt*8)*48;
    int lane = threadIdx.x&63;
    for(int o=0;o<20;o++){
        float s1=0, s2=0;
        for(int e=threadIdx.x; e<384; e+=blockDim.x){
            float val = vl[o*384+e] + rbuf[((size_t)(b*20+o))*SPAT + sb + e];
            h[((size_t)(b*80+grp*20+o))*SPAT + sb + e] = val;
            s1 += val; s2 += val*val;
        }
        float r1 = wred(s1), r2 = wred(s2);
        if(lane==0){ atomicAdd(&stats[(b*80+grp*20+o)*2], r1); atomicAdd(&stats[(b*80+grp*20+o)*2+1], r2); }
    }
}

// ---------------- layer-end gelu (in place) + full stats refresh ----------------
__global__ void k_zstats(float* stats){
    if(threadIdx.x<320) stats[threadIdx.x]=0.0f;
}
__global__ void k_gelu(float* __restrict__ h, float* __restrict__ stats){
    int blk = blockIdx.x;
    int chunk = blk%48; int ch = (blk/48)%80; int b = blk/3840;
    size_t base = ((size_t)(b*80+ch))*SPAT + chunk*4096;
    float s1=0,s2=0;
    for(int e=threadIdx.x;e<4096;e+=blockDim.x){
        float g = geluf(h[base+e]);
        h[base+e]=g;
        s1+=g; s2+=g*g;
    }
    float r1=wred(s1), r2=wred(s2);
    if((threadIdx.x&63)==0){ atomicAdd(&stats[(b*80+ch)*2], r1); atomicAdd(&stats[(b*80+ch)*2+1], r2); }
}

// ---------------- output head ----------------
__global__ void k_head(const float* __restrict__ h, const float* __restrict__ qw1,
                       const float* __restrict__ qb1, const float* __restrict__ qw2,
                       const float* __restrict__ qb2, float* __restrict__ out){
    __shared__ float inl[3840];
    __shared__ float t1l[3840];
    __shared__ float w1l[1600], w2l[1600], b1l[80], b2l[20];
    int b = blockIdx.x>>12, xy = blockIdx.x&4095;
    for(int t=threadIdx.x;t<3840;t+=blockDim.x){
        int ch = t/48, z = t%48;
        inl[t] = h[((size_t)(b*80+ch))*SPAT + xy*48 + z];
    }
    for(int g=0; g<4; g++){
        __syncthreads();
        for(int t=threadIdx.x;t<1600;t+=blockDim.x){ w1l[t]=qw1[g*1600+t]; w2l[t]=qw2[g*1600+t]; }
        if(threadIdx.x<80) b1l[threadIdx.x]=qb1[g*80+threadIdx.x];
        if(threadIdx.x<20) b2l[threadIdx.x]=qb2[g*20+threadIdx.x];
        __syncthreads();
        for(int oi=threadIdx.x; oi<3840; oi+=blockDim.x){
            int o80 = oi/48, z = oi%48;
            float a = b1l[o80];
            const float* iv = inl + (g*20)*48 + z;
            const float* w = w1l + o80*20;
            #pragma unroll
            for(int j=0;j<20;j++) a += iv[j*48]*w[j];
            t1l[o80*48+z] = geluf(a);
        }
        __syncthreads();
        for(int oi=threadIdx.x; oi<960; oi+=blockDim.x){
            int o = oi/48, z = oi%48;
            float a = b2l[o];
            const float* w = w2l + o*80;
            #pragma unroll 20
            for(int j=0;j<80;j++) a += t1l[j*48+z]*w[j];
            out[(((size_t)(b*4096)+xy)*48 + z)*80 + g*20 + o] = a;
        }
    }
}

extern "C" void kernel_launch(void* const* d_in, const int* in_sizes, int n_in,
                              void* d_out, int out_size, void* d_ws, size_t ws_size,
                              hipStream_t stream){
    (void)in_sizes; (void)n_in; (void)out_size;
    const float* x    = (const float*)d_in[0];
    const float* p_w  = (const float*)d_in[1];
    const float* p_b  = (const float*)d_in[2];
    const float* spec = (const float*)d_in[3];
    const float* w1   = (const float*)d_in[4];
    const float* b1   = (const float*)d_in[5];
    const float* w2   = (const float*)d_in[6];
    const float* b2   = (const float*)d_in[7];
    const float* ww   = (const float*)d_in[8];
    const float* wb   = (const float*)d_in[9];
    const float* qw1  = (const float*)d_in[10];
    const float* qb1  = (const float*)d_in[11];
    const float* qw2  = (const float*)d_in[12];
    const float* qb2  = (const float*)d_in[13];
    float* out = (float*)d_out;
    float* ws  = (float*)d_ws;

    if(ws_size < (size_t)49158032*4) return;  // need ~197 MB scratch

    float* h     = ws;                          // 31,457,280
    float* rbuf  = ws + 31457280;               //  7,864,320
    float* zbuf  = ws + 39321600;               //  7,864,320 (region reused below)
    float* fbuf  = zbuf;                        //    491,520
    float* gbuf  = zbuf + 491520;               //    163,840
    float* iyb   = zbuf + 655360;               //  2,621,440
    float* ybuf  = ws + 47185920;               //  1,966,080
    float* stats = ws + 49152000;               //        320
    float* stat2 = ws + 49152320;               //         80
    float* tab   = ws + 49152400;               //      5,632

    hipMemsetAsync(stats, 0, 400*sizeof(float), stream);
    k_tables<<<1,256,0,stream>>>(tab);
    k_lift<<<8192,256,0,stream>>>(x, p_w, p_b, h, stats);

    static const int ORD3[4][3] = {{0,1,2},{1,2,3},{2,3,0},{3,0,1}};
    for(int l=0;l<4;l++){
        for(int i=0;i<4;i++){
            int li = l*4+i;
            int g0=ORD3[i][0], g1=ORD3[i][1], g2=ORD3[i][2];
            k_passA<<<8192,256,0,stream>>>(h, ww, wb, rbuf, zbuf, tab, li, g0,g1,g2);
            k_passB<<<7680,128,0,stream>>>(zbuf, ybuf, tab);
            k_passC<<<1920,128,0,stream>>>(ybuf, fbuf, stats, tab, g0,g1,g2);
            k_spec<<<320,64,0,stream>>>(fbuf, spec, gbuf, stats, stat2, li, i);
            k_inv<<<2560,128,0,stream>>>(gbuf, iyb, stat2, tab);
            k_passD<<<1024,256,0,stream>>>(iyb, rbuf, w1, b1, w2, b2, h, stats, stat2, tab, li, i);
        }
        if(l<3){
            k_zstats<<<1,512,0,stream>>>(stats);
            k_gelu<<<7680,256,0,stream>>>(h, stats);
        }
    }
    k_head<<<8192,256,0,stream>>>(h, qw1, qb1, qw2, qb2, out);
}

// Round 2
// 4757.819 us; speedup vs baseline: 4.5033x; 4.5033x over previous
//
#include <hip/hip_runtime.h>
#include <math.h>

#define SPAT 196608   // 64*64*48
#define EPSV 1e-5f

__device__ __forceinline__ float geluf(float x){
    return 0.5f*x*(1.0f + erff(x*0.70710678118654752440f));
}
__device__ __forceinline__ float wred(float v){
    #pragma unroll
    for(int o=32;o>0;o>>=1) v += __shfl_down(v,o);
    return v;
}

// ---------------- twiddle tables ----------------
// tab layout (floats):
// 0:    cz  [z*8+k]    384
// 384:  sz  [z*8+k]    384
// 768:  czT [k*48+z]   384   (passA fwd z-DFT, passD z-inverse transposed)
// 1152: szT [k*48+z]   384
// 1536: cxy [y*16+ki]  1024  (fused inverse)
// 2560: sxy [y*16+ki]  1024
// 3584: cxyT[ki*64+y]  1024  (passB / passC forward)
// 4608: sxyT[ki*64+y]  1024
__global__ void k_tables(float* tab){
    for(int idx=threadIdx.x; idx<384; idx+=blockDim.x){
        int z = idx>>3, k = idx&7;
        double a = 6.283185307179586476925286766559 * (double)((k*z)%48) / 48.0;
        float c = (float)cos(a), s = (float)sin(a);
        tab[idx]=c; tab[384+idx]=s;
        tab[768 + k*48+z]=c; tab[1152 + k*48+z]=s;
    }
    for(int idx=threadIdx.x; idx<1024; idx+=blockDim.x){
        int y = idx>>4, ki = idx&15;
        int ka = ki<8 ? ki : ki+48;
        double a = 6.283185307179586476925286766559 * (double)((ka*y)%64) / 64.0;
        float c=(float)cos(a), s=(float)sin(a);
        tab[1536+idx]=c; tab[2560+idx]=s;
        tab[3584 + ki*64+y]=c; tab[4608 + ki*64+y]=s;
    }
}

// ---------------- lifting (4 xy per block) + partial stats ----------------
__global__ void __launch_bounds__(256) k_lift(const float* __restrict__ x,
                       const float* __restrict__ pw, const float* __restrict__ pb,
                       float* __restrict__ h, float* __restrict__ partL){
    __shared__ float inlT[40*49];
    __shared__ float wl[1040];
    __shared__ float bl[80];
    __shared__ float sstat[160];
    int blk = blockIdx.x; int b = blk>>10; int xy0 = (blk&1023)*4;
    int tid = threadIdx.x;
    for(int t=tid;t<1040;t+=256) wl[t]=pw[t];
    for(int t=tid;t<80;t+=256)   bl[t]=pb[t];
    if(tid<160) sstat[tid]=0.0f;
    float s1a[15], s2a[15];
    #pragma unroll
    for(int k=0;k<15;k++){ s1a[k]=0.0f; s2a[k]=0.0f; }
    for(int q=0;q<4;q++){
        int xy = xy0+q;
        __syncthreads();
        const float4* xp4 = (const float4*)(x + ((size_t)(b*4096+xy))*1920);
        for(int u=tid; u<480; u+=256){
            float4 v = xp4[u];
            int li = u*4; int z = li/40, c = li%40;  // c..c+3 never wraps
            inlT[c*49+z]=v.x; inlT[(c+1)*49+z]=v.y; inlT[(c+2)*49+z]=v.z; inlT[(c+3)*49+z]=v.w;
        }
        __syncthreads();
        float gx = (float)(xy>>6)*(1.0f/63.0f);
        float gy = (float)(xy&63)*(1.0f/63.0f);
        #pragma unroll
        for(int k=0;k<15;k++){
            int oi = tid + k*256;
            int g = oi/960, c20 = (oi/48)%20, z = oi%48;
            const float* w = wl + g*260;
            const float* iv = inlT + (g*10)*49 + z;
            float acc = bl[g*20+c20];
            #pragma unroll
            for(int j=0;j<10;j++) acc += iv[j*49]*w[j*20+c20];
            acc += gx*w[200+c20] + gy*w[220+c20] + ((float)z*(1.0f/47.0f))*w[240+c20];
            h[((size_t)(b*80) + (size_t)(oi/48))*SPAT + (size_t)xy*48 + z] = acc;
            s1a[k]+=acc; s2a[k]+=acc*acc;
        }
    }
    __syncthreads();
    #pragma unroll
    for(int k=0;k<15;k++){
        int ch = (tid + k*256)/48;
        atomicAdd(&sstat[ch*2],   s1a[k]);
        atomicAdd(&sstat[ch*2+1], s2a[k]);
    }
    __syncthreads();
    if(tid<160) partL[(size_t)blk*160 + tid] = sstat[tid];
}

__global__ void k_red0(const float* __restrict__ partL, float* __restrict__ stats){
    int v = blockIdx.x; int b = v/160, idx = v%160;
    int lane = threadIdx.x;
    float s=0.0f;
    for(int p=lane;p<1024;p+=64) s += partL[(size_t)(b*1024+p)*160 + idx];
    s = wred(s);
    if(lane==0) stats[b*160+idx]=s;
}

// ---------------- pass A: gather + z-DFT + residual conv ----------------
__global__ void k_passA(const float* __restrict__ h, const float* __restrict__ ww,
                        const float* __restrict__ wb, float* __restrict__ rbuf,
                        float* __restrict__ zbuf, const float* __restrict__ tab,
                        int li, int g0, int g1, int g2){
    __shared__ __align__(16) float vl[60*52];   // 60ch x 48z, row stride 52
    __shared__ float wl[1600];
    __shared__ float wsum[400];
    __shared__ float wbl[20];
    __shared__ __align__(16) float czl[8*52], szl[8*52];  // [k][z], stride 52
    int b = blockIdx.x >> 12; int xy = blockIdx.x & 4095;
    int dgx[3] = {g0,g1,g2};
    for(int u=threadIdx.x; u<720; u+=blockDim.x){
        int d = u/12, zq = u%12;
        int ch = dgx[d/20]*20 + d%20;
        float4 v = *(const float4*)(h + ((size_t)(b*80+ch))*SPAT + (size_t)xy*48 + zq*4);
        *(float4*)(vl + d*52 + zq*4) = v;
    }
    for(int t=threadIdx.x; t<1600; t+=blockDim.x) wl[t] = ww[li*1600 + t];
    for(int t=threadIdx.x; t<20;   t+=blockDim.x) wbl[t] = wb[li*20 + t];
    for(int t=threadIdx.x; t<384;  t+=blockDim.x){
        int k = t/48, z = t%48;
        czl[k*52+z]=tab[768+t]; szl[k*52+z]=tab[1152+t];
    }
    __syncthreads();
    for(int t=threadIdx.x; t<400; t+=blockDim.x){
        int o = t/20, c = t%20;
        wsum[t] = wl[o*80+c] + wl[o*80+20+c];
    }
    __syncthreads();
    if(threadIdx.x < 240){
        // z-DFT: (d-pair, k)
        int dp = threadIdx.x>>3, k = threadIdx.x&7;
        int d0 = dp*2;
        const float4* va = (const float4*)(vl + d0*52);
        const float4* vb = (const float4*)(vl + d0*52+52);
        const float4* tc = (const float4*)(czl + k*52);
        const float4* tsv= (const float4*)(szl + k*52);
        float r0=0,i0=0,r1=0,i1=0;
        #pragma unroll
        for(int z4=0;z4<12;z4++){
            float4 c = tc[z4], s = tsv[z4], a = va[z4], e = vb[z4];
            r0 += a.x*c.x + a.y*c.y + a.z*c.z + a.w*c.w;
            i0 -= a.x*s.x + a.y*s.y + a.z*s.z + a.w*s.w;
            r1 += e.x*c.x + e.y*c.y + e.z*c.z + e.w*c.w;
            i1 -= e.x*s.x + e.y*s.y + e.z*s.z + e.w*s.w;
        }
        size_t i0x = (((size_t)(b*60+d0)*4096 + xy)*8 + k)*2;
        size_t i1x = (((size_t)(b*60+d0+1)*4096 + xy)*8 + k)*2;
        zbuf[i0x]=r0; zbuf[i0x+1]=i0; zbuf[i1x]=r1; zbuf[i1x+1]=i1;
        // residual: o x z-quads
        int o = threadIdx.x/12, zq = threadIdx.x%12;
        int z0 = zq*4;
        float4 acc = {wbl[o],wbl[o],wbl[o],wbl[o]};
        #pragma unroll
        for(int c=0;c<20;c++){
            float wv = wsum[o*20+c];
            float4 v = *(const float4*)(vl + c*52 + z0);
            acc.x += wv*v.x; acc.y += wv*v.y; acc.z += wv*v.z; acc.w += wv*v.w;
        }
        #pragma unroll
        for(int c=0;c<20;c++){
            float wv = wl[o*80+40+c];
            float4 v = *(const float4*)(vl + (20+c)*52 + z0);
            acc.x += wv*v.x; acc.y += wv*v.y; acc.z += wv*v.z; acc.w += wv*v.w;
        }
        #pragma unroll
        for(int c=0;c<20;c++){
            float wv = wl[o*80+60+c];
            float4 v = *(const float4*)(vl + (40+c)*52 + z0);
            acc.x += wv*v.x; acc.y += wv*v.y; acc.z += wv*v.z; acc.w += wv*v.w;
        }
        float* rp = rbuf + ((size_t)(b*20+o))*SPAT + (size_t)xy*48 + z0;
        *(float4*)rp = acc;
    }
}

// ---------------- pass B: forward y-DFT (64y -> 16ky) ----------------
__global__ void k_passB(const float* __restrict__ zbuf, float* __restrict__ ybuf,
                        const float* __restrict__ tab){
    __shared__ __align__(16) float zl[1024];
    __shared__ __align__(16) float cl[1056], sl[1056];  // [ki][y] stride 66
    int blk = blockIdx.x;
    int x = blk & 63; int d = (blk/64)%60; int b = blk/3840;
    const float4* src4 = (const float4*)(zbuf + ((size_t)(b*60+d)*4096 + x*64)*16);
    for(int t=threadIdx.x;t<256;t+=blockDim.x) ((float4*)zl)[t]=src4[t];
    for(int t=threadIdx.x;t<1024;t+=blockDim.x){
        int ki = t>>6, y = t&63;
        cl[ki*66+y]=tab[3584+t]; sl[ki*66+y]=tab[4608+t];
    }
    __syncthreads();
    int kyi = threadIdx.x>>3, kz = threadIdx.x&7;
    float fr=0, fi=0;
    const float2* tc = (const float2*)(cl + kyi*66);
    const float2* ts = (const float2*)(sl + kyi*66);
    for(int y2=0;y2<32;y2++){
        float2 c2 = tc[y2], s2 = ts[y2];
        float2 v0 = *(const float2*)(zl + ((2*y2)*8+kz)*2);
        float2 v1 = *(const float2*)(zl + ((2*y2+1)*8+kz)*2);
        fr += v0.x*c2.x + v0.y*s2.x + v1.x*c2.y + v1.y*s2.y;
        fi += v0.y*c2.x - v0.x*s2.x + v1.y*c2.y - v1.x*s2.y;
    }
    size_t idx = ((((size_t)(b*60+d)*64 + x)*16 + kyi)*8 + kz)*2;
    ybuf[idx]=fr; ybuf[idx+1]=fi;
}

// ---------------- pass C: forward x-DFT + instance-norm-1 fold ----------------
__global__ void k_passC(const float* __restrict__ ybuf, float* __restrict__ fbuf,
                        const float* __restrict__ stats, const float* __restrict__ tab,
                        int g0,int g1,int g2){
    __shared__ __align__(16) float yl[1056];   // [kz][x][2] stride 132
    __shared__ __align__(16) float cl[1056], sl[1056];
    int blk = blockIdx.x;
    int kyi = blk & 15; int d = (blk/16)%60; int b = blk/960;
    for(int t=threadIdx.x;t<1024;t+=blockDim.x){
        int xx = t>>4; int r = t&15;  // r = kz*2+ri
        float v = ybuf[((((size_t)(b*60+d)*64 + xx)*16 + kyi)*8)*2 + r];
        yl[(r>>1)*132 + xx*2 + (r&1)] = v;
    }
    for(int t=threadIdx.x;t<1024;t+=blockDim.x){
        int ki = t>>6, y = t&63;
        cl[ki*66+y]=tab[3584+t]; sl[ki*66+y]=tab[4608+t];
    }
    __syncthreads();
    int dgx[3]={g0,g1,g2};
    int ch = dgx[d/20]*20 + d%20;
    float s1 = stats[(b*80+ch)*2], s2 = stats[(b*80+ch)*2+1];
    float mean = s1*(1.0f/196608.0f);
    float var = s2*(1.0f/196608.0f) - mean*mean;
    float sc = rsqrtf(var + EPSV);
    int kxi = threadIdx.x>>3, kz = threadIdx.x&7;
    float fr=0, fi=0;
    const float2* tc = (const float2*)(cl + kxi*66);
    const float2* ts = (const float2*)(sl + kxi*66);
    const float2* vz = (const float2*)(yl + kz*132);
    for(int x2=0;x2<32;x2++){
        float2 c2 = tc[x2], s2v = ts[x2];
        float2 v0 = vz[2*x2], v1 = vz[2*x2+1];
        fr += v0.x*c2.x + v0.y*s2v.x + v1.x*c2.y + v1.y*s2v.y;
        fi += v0.y*c2.x - v0.x*s2v.x + v1.y*c2.y - v1.x*s2v.y;
    }
    fr *= sc; fi *= sc;
    if(kxi==0 && kyi==0 && kz==0){ fr=0.0f; fi=0.0f; }
    size_t idx = ((((size_t)(b*60+d)*16 + kxi)*16 + kyi)*8 + kz)*2;
    fbuf[idx]=fr; fbuf[idx+1]=fi;
}

// ---------------- spectral multiply (+ stat2 zeroing) ----------------
__global__ void k_spec(const float* __restrict__ fbuf, const float* __restrict__ sw,
                       float* __restrict__ gbuf, float* __restrict__ stat2, int li){
    int blk = blockIdx.x;
    int m1p = blk & 3, o = (blk>>2)%20, q = blk/80;
    if(q==0 && m1p==0 && threadIdx.x<2){
        int b = threadIdx.x;
        stat2[(b*20+o)*2]=0.f; stat2[(b*20+o)*2+1]=0.f;
    }
    int offx = (q&1)*8, offy = (q>>1)*8;
    int t = threadIdx.x;
    int m1 = m1p*2 + (t>>5);
    int m2 = (t>>2)&7;
    int m3 = (t&3)*2;
    int tw = m1*64 + m2*8 + m3;
    int kxi = m1+offx, kyi = m2+offy;
    int fo = (kxi*16 + kyi)*8 + m3;
    const float4* wp  = (const float4*)(sw + ((size_t)((li*4+q)*1600) + o)*1024 + (size_t)tw*2);
    const float4* f00 = (const float4*)(fbuf + (size_t)fo*2);
    float r00=0,i00=0,r01=0,i01=0, r10=0,i10=0,r11=0,i11=0;
    #pragma unroll 4
    for(int c=0;c<20;c++){
        float4 wa = wp[(size_t)c*5120];
        float4 wb4= wp[(size_t)(c+20)*5120];
        float wr0 = wa.x + wb4.x, wi0 = wa.y + wb4.y, wr1 = wa.z + wb4.z, wi1 = wa.w + wb4.w;
        float4 f0 = f00[(size_t)c*1024];
        float4 f1 = f00[(size_t)(60+c)*1024];
        r00 += f0.x*wr0 - f0.y*wi0; i00 += f0.x*wi0 + f0.y*wr0;
        r01 += f0.z*wr1 - f0.w*wi1; i01 += f0.z*wi1 + f0.w*wr1;
        r10 += f1.x*wr0 - f1.y*wi0; i10 += f1.x*wi0 + f1.y*wr0;
        r11 += f1.z*wr1 - f1.w*wi1; i11 += f1.z*wi1 + f1.w*wr1;
    }
    #pragma unroll 4
    for(int c=0;c<40;c++){
        float4 wa = wp[(size_t)(c+40)*5120];
        float4 f0 = f00[(size_t)(20+c)*1024];
        float4 f1 = f00[(size_t)(80+c)*1024];
        r00 += f0.x*wa.x - f0.y*wa.y; i00 += f0.x*wa.y + f0.y*wa.x;
        r01 += f0.z*wa.z - f0.w*wa.w; i01 += f0.z*wa.w + f0.w*wa.z;
        r10 += f1.x*wa.x - f1.y*wa.y; i10 += f1.x*wa.y + f1.y*wa.x;
        r11 += f1.z*wa.z - f1.w*wa.w; i11 += f1.z*wa.w + f1.w*wa.z;
    }
    float4* g0 = (float4*)(gbuf + (size_t)o*4096 + fo*2);
    float4* g1 = (float4*)(gbuf + (size_t)(20+o)*4096 + fo*2);
    *g0 = make_float4(r00,i00,r01,i01);
    *g1 = make_float4(r10,i10,r11,i11);
}

// ---------------- fused inverse x + y (+ Parseval stats for norm2) ----------------
__global__ void k_inv(const float* __restrict__ gbuf, float* __restrict__ iybuf,
                      float* __restrict__ stat2, const float* __restrict__ tab){
    __shared__ __align__(16) float gl[4096];
    __shared__ float tmp[256];
    __shared__ __align__(16) float cl[1024], sl[1024];
    __shared__ float ig[4];
    int blk = blockIdx.x;
    int nx = blk&63, o = (blk>>6)%20, b = blk/1280;
    const float4* src4 = (const float4*)(gbuf + (size_t)(b*20+o)*4096);
    for(int t=threadIdx.x;t<1024;t+=blockDim.x) ((float4*)gl)[t]=src4[t];
    for(int t=threadIdx.x;t<256;t+=blockDim.x){
        ((float4*)cl)[t]=((const float4*)(tab+1536))[t];
        ((float4*)sl)[t]=((const float4*)(tab+2560))[t];
    }
    __syncthreads();
    {
        int kyi = threadIdx.x>>3, kz = threadIdx.x&7;
        float ar=0, ai=0;
        #pragma unroll 4
        for(int kxi=0;kxi<16;kxi++){
            float gr = gl[((kxi*16+kyi)*8+kz)*2], gi2 = gl[((kxi*16+kyi)*8+kz)*2+1];
            float c = cl[nx*16+kxi], s = sl[nx*16+kxi];
            ar += gr*c - gi2*s;
            ai += gi2*c + gr*s;
        }
        tmp[threadIdx.x*2]   = ar*(1.0f/64.0f);
        tmp[threadIdx.x*2+1] = ai*(1.0f/64.0f);
    }
    __syncthreads();
    float p1=0,p2=0;
    for(int j=0;j<4;j++){
        int out = threadIdx.x + j*128;
        int ny = out>>3, kz = out&7;
        float ar=0, ai=0;
        #pragma unroll 4
        for(int kyi=0;kyi<16;kyi++){
            float vr = tmp[(kyi*8+kz)*2], vi = tmp[(kyi*8+kz)*2+1];
            float c = cl[ny*16+kyi], s = sl[ny*16+kyi];
            ar += vr*c - vi*s;
            ai += vi*c + vr*s;
        }
        ar *= (1.0f/64.0f); ai *= (1.0f/64.0f);
        size_t idx = ((((size_t)(b*20+o)*64+nx)*64+ny)*8+kz)*2;
        iybuf[idx]=ar; iybuf[idx+1]=ai;
        if(kz==0){ p1 += ar; p2 += ar*ar; }
        else p2 += 2.0f*(ar*ar+ai*ai);
    }
    p2 *= (1.0f/48.0f);
    float r1=wred(p1), r2=wred(p2);
    int wv = threadIdx.x>>6;
    if((threadIdx.x&63)==0){ ig[wv*2]=r1; ig[wv*2+1]=r2; }
    __syncthreads();
    if(threadIdx.x==0){
        atomicAdd(&stat2[(b*20+o)*2],   ig[0]+ig[2]);
        atomicAdd(&stat2[(b*20+o)*2+1], ig[1]+ig[3]);
    }
}

// ---------------- pass D: z-inverse + norm2 + MLP + residual add + h write + partial stats ----------------
__global__ void __launch_bounds__(256) k_passD(
        const float* __restrict__ iybuf, const float* __restrict__ rbuf,
        const float* __restrict__ w1, const float* __restrict__ b1,
        const float* __restrict__ w2, const float* __restrict__ b2,
        float* __restrict__ h, float* __restrict__ partD,
        const float* __restrict__ stat2, const float* __restrict__ tab,
        int li, int grp){
    __shared__ __align__(16) float dl[2560];
    __shared__ __align__(16) float vl[20*392];
    __shared__ float w1l[400], w2l[400], b1l[20], b2l[20], m2l[20], s2l[20];
    __shared__ float czl[384], szl[384];   // [k][z] transposed
    __shared__ float red[480];
    int blk = blockIdx.x;
    int nyt = blk&7, nx=(blk>>3)&63, b = blk>>9;
    int tid = threadIdx.x;
    for(int u=tid; u<640; u+=256){
        int o = u>>5, j = u&31;
        const float4* s4 = (const float4*)(iybuf + ((((size_t)(b*20+o)*64+nx)*64 + nyt*8)*16));
        ((float4*)dl)[o*32+j] = s4[j];
    }
    for(int t=tid;t<400;t+=256){ w1l[t]=w1[li*400+t]; w2l[t]=w2[li*400+t]; }
    if(tid<20){
        b1l[tid]=b1[li*20+tid]; b2l[tid]=b2[li*20+tid];
        float S1 = stat2[(b*20+tid)*2], S2 = stat2[(b*20+tid)*2+1];
        float mean = S1*(1.0f/196608.0f);
        float var = S2*(1.0f/196608.0f) - mean*mean;
        m2l[tid]=mean; s2l[tid]=rsqrtf(var+EPSV);
    }
    for(int t=tid;t<384;t+=256){ czl[t]=tab[768+t]; szl[t]=tab[1152+t]; }
    __syncthreads();
    for(int idx=tid; idx<7680; idx+=256){
        int o = idx/384, p = idx%384;
        int ny = p/48, nz = p%48;
        const float* dd = dl + o*128 + ny*16;
        float acc = dd[0];
        #pragma unroll
        for(int k=1;k<8;k++)
            acc += 2.0f*(dd[k*2]*czl[k*48+nz] - dd[k*2+1]*szl[k*48+nz]);
        float xv = acc*(1.0f/48.0f);
        vl[o*392+p] = (xv - m2l[o])*s2l[o];
    }
    __syncthreads();
    for(int p=tid; p<384; p+=256){
        float vj[20], t1[20];
        #pragma unroll
        for(int j2=0;j2<20;j2++) vj[j2]=vl[j2*392+p];
        #pragma unroll
        for(int oo=0;oo<20;oo++){
            float a = b1l[oo];
            #pragma unroll
            for(int j2=0;j2<20;j2++) a += vj[j2]*w1l[oo*20+j2];
            t1[oo] = geluf(a);
        }
        #pragma unroll
        for(int oo=0;oo<20;oo++){
            float a = b2l[oo];
            #pragma unroll
            for(int j2=0;j2<20;j2++) a += t1[j2]*w2l[oo*20+j2];
            vl[oo*392+p] = a;
        }
    }
    __syncthreads();
    int sb = (nx*64 + nyt*8)*48;
    if(tid<240){
        int o = tid/12, s = tid%12;
        const float4* vo4 = (const float4*)(vl + o*392);
        const float4* rb4 = (const float4*)(rbuf + (size_t)(b*20+o)*SPAT + sb);
        float4* hp4 = (float4*)(h + (size_t)(b*80+grp*20+o)*SPAT + sb);
        float s1=0,s2=0;
        #pragma unroll
        for(int j=0;j<8;j++){
            int qq = s + j*12;
            float4 v = vo4[qq], r = rb4[qq];
            v.x+=r.x; v.y+=r.y; v.z+=r.z; v.w+=r.w;
            hp4[qq]=v;
            s1 += v.x+v.y+v.z+v.w;
            s2 += v.x*v.x+v.y*v.y+v.z*v.z+v.w*v.w;
        }
        red[tid*2]=s1; red[tid*2+1]=s2;
    }
    __syncthreads();
    if(tid<40){
        int o=tid>>1, w=tid&1;
        float s=0;
        #pragma unroll
        for(int t2=0;t2<12;t2++) s += red[(o*12+t2)*2+w];
        partD[(size_t)blk*40 + o*2 + w] = s;
    }
}

__global__ void k_redD(const float* __restrict__ partD, float* __restrict__ stats, int grp){
    int v = blockIdx.x; int b = v/20, o = v%20;
    int lane = threadIdx.x;
    float s1=0,s2=0;
    for(int j=lane;j<512;j+=64){
        const float* p = partD + (size_t)(b*512+j)*40 + o*2;
        s1 += p[0]; s2 += p[1];
    }
    s1=wred(s1); s2=wred(s2);
    if(lane==0){
        stats[(b*80+grp*20+o)*2]=s1;
        stats[(b*80+grp*20+o)*2+1]=s2;
    }
}

// ---------------- layer-end gelu (in place) + stats refresh ----------------
__global__ void k_zstats(float* stats){
    if(threadIdx.x<320) stats[threadIdx.x]=0.0f;
}
__global__ void k_gelu(float* __restrict__ h, float* __restrict__ stats){
    __shared__ float sg[8];
    int blk = blockIdx.x;
    int chunk = blk%48; int ch = (blk/48)%80; int b = blk/3840;
    size_t base = ((size_t)(b*80+ch))*SPAT + (size_t)chunk*4096;
    float4* hp = (float4*)(h+base);
    float s1=0,s2=0;
    for(int e=threadIdx.x;e<1024;e+=blockDim.x){
        float4 v = hp[e];
        v.x=geluf(v.x); v.y=geluf(v.y); v.z=geluf(v.z); v.w=geluf(v.w);
        hp[e]=v;
        s1 += v.x+v.y+v.z+v.w;
        s2 += v.x*v.x+v.y*v.y+v.z*v.z+v.w*v.w;
    }
    float r1=wred(s1), r2=wred(s2);
    int wv = threadIdx.x>>6;
    if((threadIdx.x&63)==0){ sg[wv*2]=r1; sg[wv*2+1]=r2; }
    __syncthreads();
    if(threadIdx.x==0){
        atomicAdd(&stats[(b*80+ch)*2],   sg[0]+sg[2]+sg[4]+sg[6]);
        atomicAdd(&stats[(b*80+ch)*2+1], sg[1]+sg[3]+sg[5]+sg[7]);
    }
}

// ---------------- output head ----------------
__global__ void k_head(const float* __restrict__ h, const float* __restrict__ qw1,
                       const float* __restrict__ qb1, const float* __restrict__ qw2,
                       const float* __restrict__ qb2, float* __restrict__ out){
    __shared__ float inl[3840];
    __shared__ float t1l[3840];
    __shared__ float w1l[1600], w2l[1600], b1l[80], b2l[20];
    int b = blockIdx.x>>12, xy = blockIdx.x&4095;
    for(int t=threadIdx.x;t<3840;t+=blockDim.x){
        int ch = t/48, z = t%48;
        inl[t] = h[((size_t)(b*80+ch))*SPAT + (size_t)xy*48 + z];
    }
    for(int g=0; g<4; g++){
        __syncthreads();
        for(int t=threadIdx.x;t<1600;t+=blockDim.x){ w1l[t]=qw1[g*1600+t]; w2l[t]=qw2[g*1600+t]; }
        if(threadIdx.x<80) b1l[threadIdx.x]=qb1[g*80+threadIdx.x];
        if(threadIdx.x<20) b2l[threadIdx.x]=qb2[g*20+threadIdx.x];
        __syncthreads();
        for(int oi=threadIdx.x; oi<3840; oi+=blockDim.x){
            int o80 = oi/48, z = oi%48;
            float a = b1l[o80];
            const float* iv = inl + (g*20)*48 + z;
            const float* w = w1l + o80*20;
            #pragma unroll
            for(int j=0;j<20;j++) a += iv[j*48]*w[j];
            t1l[o80*48+z] = geluf(a);
        }
        __syncthreads();
        for(int oi=threadIdx.x; oi<960; oi+=blockDim.x){
            int o = oi/48, z = oi%48;
            float a = b2l[o];
            const float* w = w2l + o*80;
            #pragma unroll 20
            for(int j=0;j<80;j++) a += t1l[j*48+z]*w[j];
            out[(((size_t)(b*4096)+xy)*48 + z)*80 + g*20 + o] = a;
        }
    }
}

extern "C" void kernel_launch(void* const* d_in, const int* in_sizes, int n_in,
                              void* d_out, int out_size, void* d_ws, size_t ws_size,
                              hipStream_t stream){
    (void)in_sizes; (void)n_in; (void)out_size;
    const float* x    = (const float*)d_in[0];
    const float* p_w  = (const float*)d_in[1];
    const float* p_b  = (const float*)d_in[2];
    const float* spec = (const float*)d_in[3];
    const float* w1   = (const float*)d_in[4];
    const float* b1   = (const float*)d_in[5];
    const float* w2   = (const float*)d_in[6];
    const float* b2   = (const float*)d_in[7];
    const float* ww   = (const float*)d_in[8];
    const float* wb   = (const float*)d_in[9];
    const float* qw1  = (const float*)d_in[10];
    const float* qb1  = (const float*)d_in[11];
    const float* qw2  = (const float*)d_in[12];
    const float* qb2  = (const float*)d_in[13];
    float* out = (float*)d_out;
    float* ws  = (float*)d_ws;

    if(ws_size < (size_t)49158032*4) return;  // ~197 MB scratch

    float* h     = ws;                          // 31,457,280
    float* rbuf  = ws + 31457280;               //  7,864,320
    float* zbuf  = ws + 39321600;               //  7,864,320 (region reused)
    float* fbuf  = zbuf;                        //    491,520
    float* gbuf  = zbuf + 491520;               //    163,840
    float* iyb   = zbuf + 655360;               //  2,621,440 (ends 3,276,800)
    float* partL = zbuf;                        //    327,680 (lift-time only)
    float* partD = zbuf + 3276800;              //     40,960 (passD->redD only)
    float* ybuf  = ws + 47185920;               //  1,966,080
    float* stats = ws + 49152000;               //        320
    float* stat2 = ws + 49152320;               //         80
    float* tab   = ws + 49152400;               //      5,632

    k_tables<<<1,256,0,stream>>>(tab);
    k_lift<<<2048,256,0,stream>>>(x, p_w, p_b, h, partL);
    k_red0<<<320,64,0,stream>>>(partL, stats);

    static const int ORD3[4][3] = {{0,1,2},{1,2,3},{2,3,0},{3,0,1}};
    for(int l=0;l<4;l++){
        for(int i=0;i<4;i++){
            int li = l*4+i;
            int g0=ORD3[i][0], g1=ORD3[i][1], g2=ORD3[i][2];
            k_passA<<<8192,256,0,stream>>>(h, ww, wb, rbuf, zbuf, tab, li, g0,g1,g2);
            k_passB<<<7680,128,0,stream>>>(zbuf, ybuf, tab);
            k_passC<<<1920,128,0,stream>>>(ybuf, fbuf, stats, tab, g0,g1,g2);
            k_spec<<<320,64,0,stream>>>(fbuf, spec, gbuf, stat2, li);
            k_inv<<<2560,128,0,stream>>>(gbuf, iyb, stat2, tab);
            k_passD<<<1024,256,0,stream>>>(iyb, rbuf, w1, b1, w2, b2, h, partD, stat2, tab, li, i);
            k_redD<<<40,64,0,stream>>>(partD, stats, i);
        }
        if(l<3){
            k_zstats<<<1,512,0,stream>>>(stats);
            k_gelu<<<7680,256,0,stream>>>(h, stats);
        }
    }
    k_head<<<8192,256,0,stream>>>(h, qw1, qb1, qw2, qb2, out);
}

// Round 3
// 4086.786 us; speedup vs baseline: 5.2427x; 1.1642x over previous
//
#include <hip/hip_runtime.h>
#include <math.h>

#define SPAT 196608   // 64*64*48
#define EPSV 1e-5f

__device__ __forceinline__ float geluf(float x){
    return 0.5f*x*(1.0f + erff(x*0.70710678118654752440f));
}
__device__ __forceinline__ float wred(float v){
    #pragma unroll
    for(int o=32;o>0;o>>=1) v += __shfl_down(v,o);
    return v;
}

// ---------------- twiddle tables ----------------
// 0:    cz  [z*8+k]    384
// 384:  sz  [z*8+k]    384
// 768:  czT [k*48+z]   384   (zdft fwd, passD z-inverse)
// 1152: szT [k*48+z]   384
// 1536: cxy [y*16+ki]  1024  (fused inverse)
// 2560: sxy [y*16+ki]  1024
// 3584: cxyT[ki*64+y]  1024  (ydft / xdft forward)
// 4608: sxyT[ki*64+y]  1024
__global__ void k_tables(float* tab){
    for(int idx=threadIdx.x; idx<384; idx+=blockDim.x){
        int z = idx>>3, k = idx&7;
        double a = 6.283185307179586476925286766559 * (double)((k*z)%48) / 48.0;
        float c = (float)cos(a), s = (float)sin(a);
        tab[idx]=c; tab[384+idx]=s;
        tab[768 + k*48+z]=c; tab[1152 + k*48+z]=s;
    }
    for(int idx=threadIdx.x; idx<1024; idx+=blockDim.x){
        int y = idx>>4, ki = idx&15;
        int ka = ki<8 ? ki : ki+48;
        double a = 6.283185307179586476925286766559 * (double)((ka*y)%64) / 64.0;
        float c=(float)cos(a), s=(float)sin(a);
        tab[1536+idx]=c; tab[2560+idx]=s;
        tab[3584 + ki*64+y]=c; tab[4608 + ki*64+y]=s;
    }
}

// ---------------- lifting (4 xy per block) + partial stats ----------------
__global__ void __launch_bounds__(256) k_lift(const float* __restrict__ x,
                       const float* __restrict__ pw, const float* __restrict__ pb,
                       float* __restrict__ h, float* __restrict__ partL){
    __shared__ float inlT[40*49];
    __shared__ float wl[1040];
    __shared__ float bl[80];
    __shared__ float sstat[160];
    int blk = blockIdx.x; int b = blk>>10; int xy0 = (blk&1023)*4;
    int tid = threadIdx.x;
    for(int t=tid;t<1040;t+=256) wl[t]=pw[t];
    for(int t=tid;t<80;t+=256)   bl[t]=pb[t];
    if(tid<160) sstat[tid]=0.0f;
    float s1a[15], s2a[15];
    #pragma unroll
    for(int k=0;k<15;k++){ s1a[k]=0.0f; s2a[k]=0.0f; }
    for(int q=0;q<4;q++){
        int xy = xy0+q;
        __syncthreads();
        const float4* xp4 = (const float4*)(x + ((size_t)(b*4096+xy))*1920);
        for(int u=tid; u<480; u+=256){
            float4 v = xp4[u];
            int li = u*4; int z = li/40, c = li%40;
            inlT[c*49+z]=v.x; inlT[(c+1)*49+z]=v.y; inlT[(c+2)*49+z]=v.z; inlT[(c+3)*49+z]=v.w;
        }
        __syncthreads();
        float gx = (float)(xy>>6)*(1.0f/63.0f);
        float gy = (float)(xy&63)*(1.0f/63.0f);
        #pragma unroll
        for(int k=0;k<15;k++){
            int oi = tid + k*256;
            int g = oi/960, c20 = (oi/48)%20, z = oi%48;
            const float* w = wl + g*260;
            const float* iv = inlT + (g*10)*49 + z;
            float acc = bl[g*20+c20];
            #pragma unroll
            for(int j=0;j<10;j++) acc += iv[j*49]*w[j*20+c20];
            acc += gx*w[200+c20] + gy*w[220+c20] + ((float)z*(1.0f/47.0f))*w[240+c20];
            h[((size_t)(b*80) + (size_t)(oi/48))*SPAT + (size_t)xy*48 + z] = acc;
            s1a[k]+=acc; s2a[k]+=acc*acc;
        }
    }
    __syncthreads();
    #pragma unroll
    for(int k=0;k<15;k++){
        int ch = (tid + k*256)/48;
        atomicAdd(&sstat[ch*2],   s1a[k]);
        atomicAdd(&sstat[ch*2+1], s2a[k]);
    }
    __syncthreads();
    if(tid<160) partL[(size_t)blk*160 + tid] = sstat[tid];
}

__global__ void k_red0(const float* __restrict__ partL, float* __restrict__ stats){
    int v = blockIdx.x; int b = v/160, idx = v%160;
    int lane = threadIdx.x;
    float s=0.0f;
    for(int p=lane;p<1024;p+=64) s += partL[(size_t)(b*1024+p)*160 + idx];
    s = wred(s);
    if(lane==0) stats[b*160+idx]=s;
}

// ---------------- forward z-DFT for one 20-channel group ----------------
__global__ void __launch_bounds__(256) k_zdft(const float* __restrict__ h,
        float* __restrict__ zbuf, const float* __restrict__ tab, int ch0){
    int blk = blockIdx.x;                 // grid = 2b*20*16 = 640
    int b = blk/320; int rem = blk%320; int cl = rem>>4; int xyc = rem&15;
    int xy = xyc*256 + threadIdx.x;
    const float4* hp = (const float4*)(h + ((size_t)(b*80+ch0+cl))*SPAT + (size_t)xy*48);
    float v[48];
    #pragma unroll
    for(int q=0;q<12;q++){
        float4 t = hp[q];
        v[q*4]=t.x; v[q*4+1]=t.y; v[q*4+2]=t.z; v[q*4+3]=t.w;
    }
    const float* CZ = tab+768; const float* SZ = tab+1152;
    float out[16];
    #pragma unroll
    for(int k=0;k<8;k++){
        float r=0.0f, s=0.0f;
        #pragma unroll
        for(int z=0;z<48;z++){ r += v[z]*CZ[k*48+z]; s += v[z]*SZ[k*48+z]; }
        out[k*2]=r; out[k*2+1]=-s;
    }
    float4* zp = (float4*)(zbuf + ((size_t)(b*20+cl)*4096 + xy)*16);
    #pragma unroll
    for(int q=0;q<4;q++) zp[q] = make_float4(out[q*4],out[q*4+1],out[q*4+2],out[q*4+3]);
}

// ---------------- forward y-DFT (64y -> 16ky) ----------------
__global__ void k_ydft(const float* __restrict__ zbuf, float* __restrict__ ybuf,
                       const float* __restrict__ tab){
    __shared__ __align__(16) float zl[1024];
    __shared__ __align__(16) float cl_[1056], sl_[1056];  // [ki][y] stride 66
    int blk = blockIdx.x;             // grid = 2b*20*64 = 2560
    int x = blk & 63; int d = (blk>>6)%20; int b = blk/1280;
    const float4* src4 = (const float4*)(zbuf + ((size_t)(b*20+d)*4096 + x*64)*16);
    for(int t=threadIdx.x;t<256;t+=blockDim.x) ((float4*)zl)[t]=src4[t];
    for(int t=threadIdx.x;t<1024;t+=blockDim.x){
        int ki = t>>6, y = t&63;
        cl_[ki*66+y]=tab[3584+t]; sl_[ki*66+y]=tab[4608+t];
    }
    __syncthreads();
    int kyi = threadIdx.x>>3, kz = threadIdx.x&7;
    float fr=0, fi=0;
    const float2* tc = (const float2*)(cl_ + kyi*66);
    const float2* ts = (const float2*)(sl_ + kyi*66);
    for(int y2=0;y2<32;y2++){
        float2 c2 = tc[y2], s2 = ts[y2];
        float2 v0 = *(const float2*)(zl + ((2*y2)*8+kz)*2);
        float2 v1 = *(const float2*)(zl + ((2*y2+1)*8+kz)*2);
        fr += v0.x*c2.x + v0.y*s2.x + v1.x*c2.y + v1.y*s2.y;
        fi += v0.y*c2.x - v0.x*s2.x + v1.y*c2.y - v1.x*s2.y;
    }
    size_t idx = ((((size_t)(b*20+d)*64 + x)*16 + kyi)*8 + kz)*2;
    ybuf[idx]=fr; ybuf[idx+1]=fi;
}

// ---------------- forward x-DFT + instance-norm-1 fold -> per-channel cache ----------------
__global__ void k_xdft(const float* __restrict__ ybuf, float* __restrict__ fbufC,
                       const float* __restrict__ stats, const float* __restrict__ tab,
                       int ch0){
    __shared__ __align__(16) float yl[1056];   // [kz][x][2] stride 132
    __shared__ __align__(16) float cl_[1056], sl_[1056];
    int blk = blockIdx.x;             // grid = 2b*20*16 = 640
    int kyi = blk & 15; int d = (blk>>4)%20; int b = blk/320;
    int ch = ch0 + d;
    for(int t=threadIdx.x;t<1024;t+=blockDim.x){
        int xx = t>>4; int r = t&15;
        float v = ybuf[((((size_t)(b*20+d)*64 + xx)*16 + kyi)*8)*2 + r];
        yl[(r>>1)*132 + xx*2 + (r&1)] = v;
    }
    for(int t=threadIdx.x;t<1024;t+=blockDim.x){
        int ki = t>>6, y = t&63;
        cl_[ki*66+y]=tab[3584+t]; sl_[ki*66+y]=tab[4608+t];
    }
    __syncthreads();
    float s1 = stats[(b*80+ch)*2], s2 = stats[(b*80+ch)*2+1];
    float mean = s1*(1.0f/196608.0f);
    float var = s2*(1.0f/196608.0f) - mean*mean;
    float sc = rsqrtf(var + EPSV);
    int kxi = threadIdx.x>>3, kz = threadIdx.x&7;
    float fr=0, fi=0;
    const float2* tc = (const float2*)(cl_ + kxi*66);
    const float2* ts = (const float2*)(sl_ + kxi*66);
    const float2* vz = (const float2*)(yl + kz*132);
    for(int x2=0;x2<32;x2++){
        float2 c2 = tc[x2], s2v = ts[x2];
        float2 v0 = vz[2*x2], v1 = vz[2*x2+1];
        fr += v0.x*c2.x + v0.y*s2v.x + v1.x*c2.y + v1.y*s2v.y;
        fi += v0.y*c2.x - v0.x*s2v.x + v1.y*c2.y - v1.x*s2v.y;
    }
    fr *= sc; fi *= sc;
    if(kxi==0 && kyi==0 && kz==0){ fr=0.0f; fi=0.0f; }
    size_t idx = ((size_t)(b*80+ch)*2048 + (size_t)((kxi*16+kyi)*8+kz))*2;
    fbufC[idx]=fr; fbufC[idx+1]=fi;
}

// ---------------- residual conv (global-direct, SGPR weights) ----------------
__global__ void __launch_bounds__(256) k_res(const float* __restrict__ h,
        const float* __restrict__ ww, const float* __restrict__ wb,
        float* __restrict__ rbuf, int li, int g0, int g1, int g2){
    int t = blockIdx.x*256 + threadIdx.x;      // 98304 total
    int b = t/49152; int r = t - b*49152; int xy = r/12; int zq = r%12;
    const float* W = ww + li*1600;
    float4 acc[20];
    #pragma unroll
    for(int o=0;o<20;o++){ float bv = wb[li*20+o]; acc[o]=make_float4(bv,bv,bv,bv); }
    size_t sp = (size_t)xy*48 + zq*4;
    const float* h0 = h + ((size_t)(b*80+g0*20))*SPAT + sp;
    const float* h1 = h + ((size_t)(b*80+g1*20))*SPAT + sp;
    const float* h2 = h + ((size_t)(b*80+g2*20))*SPAT + sp;
    for(int c=0;c<20;c++){
        float4 v = *(const float4*)(h0 + (size_t)c*SPAT);
        #pragma unroll
        for(int o=0;o<20;o++){
            float w = W[o*80+c] + W[o*80+20+c];
            acc[o].x += w*v.x; acc[o].y += w*v.y; acc[o].z += w*v.z; acc[o].w += w*v.w;
        }
    }
    for(int c=0;c<20;c++){
        float4 v = *(const float4*)(h1 + (size_t)c*SPAT);
        #pragma unroll
        for(int o=0;o<20;o++){
            float w = W[o*80+40+c];
            acc[o].x += w*v.x; acc[o].y += w*v.y; acc[o].z += w*v.z; acc[o].w += w*v.w;
        }
    }
    for(int c=0;c<20;c++){
        float4 v = *(const float4*)(h2 + (size_t)c*SPAT);
        #pragma unroll
        for(int o=0;o<20;o++){
            float w = W[o*80+60+c];
            acc[o].x += w*v.x; acc[o].y += w*v.y; acc[o].z += w*v.z; acc[o].w += w*v.w;
        }
    }
    #pragma unroll
    for(int o=0;o<20;o++)
        *(float4*)(rbuf + ((size_t)(b*20+o))*SPAT + sp) = acc[o];
}

// ---------------- spectral multiply (reads per-channel cache) ----------------
__global__ void k_spec(const float* __restrict__ fbufC, const float* __restrict__ sw,
                       float* __restrict__ gbuf, float* __restrict__ stat2,
                       int li, int g0, int g1, int g2){
    int blk = blockIdx.x;
    int m1p = blk & 3, o = (blk>>2)%20, q = blk/80;
    if(q==0 && m1p==0 && threadIdx.x<2){
        int b = threadIdx.x;
        stat2[(b*20+o)*2]=0.f; stat2[(b*20+o)*2+1]=0.f;
    }
    int offx = (q&1)*8, offy = (q>>1)*8;
    int t = threadIdx.x;
    int m1 = m1p*2 + (t>>5);
    int m2 = (t>>2)&7;
    int m3 = (t&3)*2;
    int tw = m1*64 + m2*8 + m3;
    int kxi = m1+offx, kyi = m2+offy;
    int fo = (kxi*16 + kyi)*8 + m3;   // even
    const float4* wp = (const float4*)(sw + (((size_t)(li*4+q)*1600) + o)*1024 + (size_t)tw*2);
    const float4* fb = (const float4*)fbufC + (fo>>1);
    float r00=0,i00=0,r01=0,i01=0, r10=0,i10=0,r11=0,i11=0;
    #pragma unroll 4
    for(int c=0;c<20;c++){
        float4 wa = wp[(size_t)c*5120];
        float4 wb4= wp[(size_t)(c+20)*5120];
        float wr0 = wa.x + wb4.x, wi0 = wa.y + wb4.y, wr1 = wa.z + wb4.z, wi1 = wa.w + wb4.w;
        float4 f0 = fb[(size_t)(g0*20+c)*1024];
        float4 f1 = fb[(size_t)(80+g0*20+c)*1024];
        r00 += f0.x*wr0 - f0.y*wi0; i00 += f0.x*wi0 + f0.y*wr0;
        r01 += f0.z*wr1 - f0.w*wi1; i01 += f0.z*wi1 + f0.w*wr1;
        r10 += f1.x*wr0 - f1.y*wi0; i10 += f1.x*wi0 + f1.y*wr0;
        r11 += f1.z*wr1 - f1.w*wi1; i11 += f1.z*wi1 + f1.w*wr1;
    }
    #pragma unroll 4
    for(int c=0;c<20;c++){
        float4 wa = wp[(size_t)(c+40)*5120];
        float4 f0 = fb[(size_t)(g1*20+c)*1024];
        float4 f1 = fb[(size_t)(80+g1*20+c)*1024];
        r00 += f0.x*wa.x - f0.y*wa.y; i00 += f0.x*wa.y + f0.y*wa.x;
        r01 += f0.z*wa.z - f0.w*wa.w; i01 += f0.z*wa.w + f0.w*wa.z;
        r10 += f1.x*wa.x - f1.y*wa.y; i10 += f1.x*wa.y + f1.y*wa.x;
        r11 += f1.z*wa.z - f1.w*wa.w; i11 += f1.z*wa.w + f1.w*wa.z;
    }
    #pragma unroll 4
    for(int c=0;c<20;c++){
        float4 wa = wp[(size_t)(c+60)*5120];
        float4 f0 = fb[(size_t)(g2*20+c)*1024];
        float4 f1 = fb[(size_t)(80+g2*20+c)*1024];
        r00 += f0.x*wa.x - f0.y*wa.y; i00 += f0.x*wa.y + f0.y*wa.x;
        r01 += f0.z*wa.z - f0.w*wa.w; i01 += f0.z*wa.w + f0.w*wa.z;
        r10 += f1.x*wa.x - f1.y*wa.y; i10 += f1.x*wa.y + f1.y*wa.x;
        r11 += f1.z*wa.z - f1.w*wa.w; i11 += f1.z*wa.w + f1.w*wa.z;
    }
    float4* gg0 = (float4*)(gbuf + (size_t)o*4096 + fo*2);
    float4* gg1 = (float4*)(gbuf + (size_t)(20+o)*4096 + fo*2);
    *gg0 = make_float4(r00,i00,r01,i01);
    *gg1 = make_float4(r10,i10,r11,i11);
}

// ---------------- fused inverse x + y (+ Parseval stats for norm2) ----------------
__global__ void k_inv(const float* __restrict__ gbuf, float* __restrict__ iybuf,
                      float* __restrict__ stat2, const float* __restrict__ tab){
    __shared__ __align__(16) float gl[4096];
    __shared__ float tmp[256];
    __shared__ __align__(16) float cl[1024], sl[1024];
    __shared__ float ig[4];
    int blk = blockIdx.x;
    int nx = blk&63, o = (blk>>6)%20, b = blk/1280;
    const float4* src4 = (const float4*)(gbuf + (size_t)(b*20+o)*4096);
    for(int t=threadIdx.x;t<1024;t+=blockDim.x) ((float4*)gl)[t]=src4[t];
    for(int t=threadIdx.x;t<256;t+=blockDim.x){
        ((float4*)cl)[t]=((const float4*)(tab+1536))[t];
        ((float4*)sl)[t]=((const float4*)(tab+2560))[t];
    }
    __syncthreads();
    {
        int kyi = threadIdx.x>>3, kz = threadIdx.x&7;
        float ar=0, ai=0;
        #pragma unroll 4
        for(int kxi=0;kxi<16;kxi++){
            float gr = gl[((kxi*16+kyi)*8+kz)*2], gi2 = gl[((kxi*16+kyi)*8+kz)*2+1];
            float c = cl[nx*16+kxi], s = sl[nx*16+kxi];
            ar += gr*c - gi2*s;
            ai += gi2*c + gr*s;
        }
        tmp[threadIdx.x*2]   = ar*(1.0f/64.0f);
        tmp[threadIdx.x*2+1] = ai*(1.0f/64.0f);
    }
    __syncthreads();
    float p1=0,p2=0;
    for(int j=0;j<4;j++){
        int out = threadIdx.x + j*128;
        int ny = out>>3, kz = out&7;
        float ar=0, ai=0;
        #pragma unroll 4
        for(int kyi=0;kyi<16;kyi++){
            float vr = tmp[(kyi*8+kz)*2], vi = tmp[(kyi*8+kz)*2+1];
            float c = cl[ny*16+kyi], s = sl[ny*16+kyi];
            ar += vr*c - vi*s;
            ai += vi*c + vr*s;
        }
        ar *= (1.0f/64.0f); ai *= (1.0f/64.0f);
        size_t idx = ((((size_t)(b*20+o)*64+nx)*64+ny)*8+kz)*2;
        iybuf[idx]=ar; iybuf[idx+1]=ai;
        if(kz==0){ p1 += ar; p2 += ar*ar; }
        else p2 += 2.0f*(ar*ar+ai*ai);
    }
    p2 *= (1.0f/48.0f);
    float r1=wred(p1), r2=wred(p2);
    int wv = threadIdx.x>>6;
    if((threadIdx.x&63)==0){ ig[wv*2]=r1; ig[wv*2+1]=r2; }
    __syncthreads();
    if(threadIdx.x==0){
        atomicAdd(&stat2[(b*20+o)*2],   ig[0]+ig[2]);
        atomicAdd(&stat2[(b*20+o)*2+1], ig[1]+ig[3]);
    }
}

// ---------------- pass D: z-inverse + norm2 + MLP + residual add + h write ----------------
__global__ void __launch_bounds__(256) k_passD(
        const float* __restrict__ iybuf, const float* __restrict__ rbuf,
        const float* __restrict__ w1, const float* __restrict__ b1,
        const float* __restrict__ w2, const float* __restrict__ b2,
        float* __restrict__ h, float* __restrict__ partD,
        const float* __restrict__ stat2, const float* __restrict__ tab,
        int li, int grp){
    __shared__ __align__(16) float dl[2560];
    __shared__ __align__(16) float vl[20*392];
    __shared__ float m2l[20], s2l[20];
    __shared__ float czl[384], szl[384];
    __shared__ float red[480];
    int blk = blockIdx.x;
    int nyt = blk&7, nx=(blk>>3)&63, b = blk>>9;
    int tid = threadIdx.x;
    for(int u=tid; u<640; u+=256){
        int o = u>>5, j = u&31;
        const float4* s4 = (const float4*)(iybuf + ((((size_t)(b*20+o)*64+nx)*64 + nyt*8)*16));
        ((float4*)dl)[o*32+j] = s4[j];
    }
    if(tid<20){
        float S1 = stat2[(b*20+tid)*2], S2 = stat2[(b*20+tid)*2+1];
        float mean = S1*(1.0f/196608.0f);
        float var = S2*(1.0f/196608.0f) - mean*mean;
        m2l[tid]=mean; s2l[tid]=rsqrtf(var+EPSV);
    }
    for(int t=tid;t<384;t+=256){ czl[t]=tab[768+t]; szl[t]=tab[1152+t]; }
    __syncthreads();
    for(int idx=tid; idx<7680; idx+=256){
        int o = idx/384, p = idx%384;
        int ny = p/48, nz = p%48;
        const float* dd = dl + o*128 + ny*16;
        float acc = dd[0];
        #pragma unroll
        for(int k=1;k<8;k++)
            acc += 2.0f*(dd[k*2]*czl[k*48+nz] - dd[k*2+1]*szl[k*48+nz]);
        float xv = acc*(1.0f/48.0f);
        vl[o*392+p] = (xv - m2l[o])*s2l[o];
    }
    __syncthreads();
    const float* W1 = w1 + li*400;
    const float* W2 = w2 + li*400;
    const float* B1 = b1 + li*20;
    const float* B2 = b2 + li*20;
    for(int p=tid; p<384; p+=256){
        float vj[20], t1[20];
        #pragma unroll
        for(int j2=0;j2<20;j2++) vj[j2]=vl[j2*392+p];
        #pragma unroll
        for(int oo=0;oo<20;oo++){
            float a = B1[oo];
            #pragma unroll
            for(int j2=0;j2<20;j2++) a += vj[j2]*W1[oo*20+j2];
            t1[oo] = geluf(a);
        }
        #pragma unroll
        for(int oo=0;oo<20;oo++){
            float a = B2[oo];
            #pragma unroll
            for(int j2=0;j2<20;j2++) a += t1[j2]*W2[oo*20+j2];
            vl[oo*392+p] = a;
        }
    }
    __syncthreads();
    int sb = (nx*64 + nyt*8)*48;
    if(tid<240){
        int o = tid/12, s = tid%12;
        const float4* vo4 = (const float4*)(vl + o*392);
        const float4* rb4 = (const float4*)(rbuf + (size_t)(b*20+o)*SPAT + sb);
        float4* hp4 = (float4*)(h + (size_t)(b*80+grp*20+o)*SPAT + sb);
        float s1=0,s2=0;
        #pragma unroll
        for(int j=0;j<8;j++){
            int qq = s + j*12;
            float4 v = vo4[qq], r = rb4[qq];
            v.x+=r.x; v.y+=r.y; v.z+=r.z; v.w+=r.w;
            hp4[qq]=v;
            s1 += v.x+v.y+v.z+v.w;
            s2 += v.x*v.x+v.y*v.y+v.z*v.z+v.w*v.w;
        }
        red[tid*2]=s1; red[tid*2+1]=s2;
    }
    __syncthreads();
    if(tid<40){
        int o=tid>>1, w=tid&1;
        float s=0;
        #pragma unroll
        for(int t2=0;t2<12;t2++) s += red[(o*12+t2)*2+w];
        partD[(size_t)blk*40 + o*2 + w] = s;
    }
}

__global__ void k_redD(const float* __restrict__ partD, float* __restrict__ stats, int grp){
    int v = blockIdx.x; int b = v/20, o = v%20;
    int lane = threadIdx.x;
    float s1=0,s2=0;
    for(int j=lane;j<512;j+=64){
        const float* p = partD + (size_t)(b*512+j)*40 + o*2;
        s1 += p[0]; s2 += p[1];
    }
    s1=wred(s1); s2=wred(s2);
    if(lane==0){
        stats[(b*80+grp*20+o)*2]=s1;
        stats[(b*80+grp*20+o)*2+1]=s2;
    }
}

// ---------------- layer-end gelu (in place) + stats refresh ----------------
__global__ void k_zstats(float* stats){
    if(threadIdx.x<320) stats[threadIdx.x]=0.0f;
}
__global__ void k_gelu(float* __restrict__ h, float* __restrict__ stats){
    __shared__ float sg[8];
    int blk = blockIdx.x;
    int chunk = blk%48; int ch = (blk/48)%80; int b = blk/3840;
    size_t base = ((size_t)(b*80+ch))*SPAT + (size_t)chunk*4096;
    float4* hp = (float4*)(h+base);
    float s1=0,s2=0;
    for(int e=threadIdx.x;e<1024;e+=blockDim.x){
        float4 v = hp[e];
        v.x=geluf(v.x); v.y=geluf(v.y); v.z=geluf(v.z); v.w=geluf(v.w);
        hp[e]=v;
        s1 += v.x+v.y+v.z+v.w;
        s2 += v.x*v.x+v.y*v.y+v.z*v.z+v.w*v.w;
    }
    float r1=wred(s1), r2=wred(s2);
    int wv = threadIdx.x>>6;
    if((threadIdx.x&63)==0){ sg[wv*2]=r1; sg[wv*2+1]=r2; }
    __syncthreads();
    if(threadIdx.x==0){
        atomicAdd(&stats[(b*80+ch)*2],   sg[0]+sg[2]+sg[4]+sg[6]);
        atomicAdd(&stats[(b*80+ch)*2+1], sg[1]+sg[3]+sg[5]+sg[7]);
    }
}

// ---------------- output head (register MLP, scalar weights) ----------------
__global__ void __launch_bounds__(256) k_head(const float* __restrict__ h,
        const float* __restrict__ qw1, const float* __restrict__ qb1,
        const float* __restrict__ qw2, const float* __restrict__ qb2,
        float* __restrict__ out){
    int t = blockIdx.x*256 + threadIdx.x;   // 393216 total
    int b = (t >= SPAT) ? 1 : 0;
    int col = t - b*SPAT;
    const float* hb = h + (size_t)(b*80)*SPAT + col;
    float* op = out + (size_t)t*80;
    for(int g=0; g<4; g++){
        float in20[20];
        #pragma unroll
        for(int j=0;j<20;j++) in20[j] = hb[(size_t)(g*20+j)*SPAT];
        float o20[20];
        #pragma unroll
        for(int o2=0;o2<20;o2++) o20[o2] = qb2[g*20+o2];
        for(int o8=0;o8<80;o8++){
            float a = qb1[g*80+o8];
            #pragma unroll
            for(int j=0;j<20;j++) a += in20[j]*qw1[g*1600 + o8*20 + j];
            a = geluf(a);
            #pragma unroll
            for(int o2=0;o2<20;o2++) o20[o2] += a*qw2[g*1600 + o2*80 + o8];
        }
        #pragma unroll
        for(int q=0;q<5;q++)
            *(float4*)(op + g*20 + q*4) = make_float4(o20[q*4],o20[q*4+1],o20[q*4+2],o20[q*4+3]);
    }
}

extern "C" void kernel_launch(void* const* d_in, const int* in_sizes, int n_in,
                              void* d_out, int out_size, void* d_ws, size_t ws_size,
                              hipStream_t stream){
    (void)in_sizes; (void)n_in; (void)out_size;
    const float* x    = (const float*)d_in[0];
    const float* p_w  = (const float*)d_in[1];
    const float* p_b  = (const float*)d_in[2];
    const float* spec = (const float*)d_in[3];
    const float* w1   = (const float*)d_in[4];
    const float* b1   = (const float*)d_in[5];
    const float* w2   = (const float*)d_in[6];
    const float* b2   = (const float*)d_in[7];
    const float* ww   = (const float*)d_in[8];
    const float* wb   = (const float*)d_in[9];
    const float* qw1  = (const float*)d_in[10];
    const float* qb1  = (const float*)d_in[11];
    const float* qw2  = (const float*)d_in[12];
    const float* qb2  = (const float*)d_in[13];
    float* out = (float*)d_out;
    float* ws  = (float*)d_ws;

    if(ws_size < (size_t)43259792*4) return;  // ~173 MB scratch

    float* h     = ws;                          // 31,457,280
    float* rbuf  = ws + 31457280;               //  7,864,320
    float* region= ws + 39321600;               //  3,276,800 (multi-use)
    float* zbuf  = region;                      //  2,621,440 (zdft -> ydft)
    float* ybuf  = region + 2621440;            //    655,360 (ydft -> xdft)
    float* gbuf  = region;                      //    163,840 (spec -> inv)
    float* iyb   = region + 163840;             //  2,621,440 (inv -> passD)
    float* partD = region + 2785280;            //     40,960 (passD -> redD)
    float* partL = region;                      //    327,680 (lift only)
    float* fbufC = ws + 42598400;               //    655,360 (per-channel cache)
    float* stats = ws + 43253760;               //        320
    float* stat2 = ws + 43254080;               //         80
    float* tab   = ws + 43254160;               //      5,632

    k_tables<<<1,256,0,stream>>>(tab);
    k_lift<<<2048,256,0,stream>>>(x, p_w, p_b, h, partL);
    k_red0<<<320,64,0,stream>>>(partL, stats);

    static const int ORD3[4][3] = {{0,1,2},{1,2,3},{2,3,0},{3,0,1}};
    for(int l=0;l<4;l++){
        for(int i=0;i<4;i++){
            int li = l*4+i;
            int g0=ORD3[i][0], g1=ORD3[i][1], g2=ORD3[i][2];
            // refresh spectral cache: all 3 groups at iter 0, newly-needed group after
            int t0 = (i==0)?0:2;
            for(int j=t0;j<3;j++){
                int tg = ORD3[i][j];
                k_zdft<<<640,256,0,stream>>>(h, zbuf, tab, tg*20);
                k_ydft<<<2560,128,0,stream>>>(zbuf, ybuf, tab);
                k_xdft<<<640,128,0,stream>>>(ybuf, fbufC, stats, tab, tg*20);
            }
            k_res<<<384,256,0,stream>>>(h, ww, wb, rbuf, li, g0,g1,g2);
            k_spec<<<320,64,0,stream>>>(fbufC, spec, gbuf, stat2, li, g0,g1,g2);
            k_inv<<<2560,128,0,stream>>>(gbuf, iyb, stat2, tab);
            k_passD<<<1024,256,0,stream>>>(iyb, rbuf, w1, b1, w2, b2, h, partD, stat2, tab, li, i);
            k_redD<<<40,64,0,stream>>>(partD, stats, i);
        }
        if(l<3){
            k_zstats<<<1,512,0,stream>>>(stats);
            k_gelu<<<7680,256,0,stream>>>(h, stats);
        }
    }
    k_head<<<1536,256,0,stream>>>(h, qw1, qb1, qw2, qb2, out);
}

// Round 4
// 3566.340 us; speedup vs baseline: 6.0078x; 1.1459x over previous
//
#include <hip/hip_runtime.h>
#include <math.h>

#define SPAT 196608   // 64*64*48
#define EPSV 1e-5f

__device__ __forceinline__ float geluf(float x){
    return 0.5f*x*(1.0f + erff(x*0.70710678118654752440f));
}
__device__ __forceinline__ float wred(float v){
    #pragma unroll
    for(int o=32;o>0;o>>=1) v += __shfl_down(v,o);
    return v;
}

// ---------------- twiddle tables ----------------
// 0:    cz  [z*8+k]    384   (unused, kept for layout stability)
// 384:  sz  [z*8+k]    384
// 768:  czT [k*48+z]   384   (k_zy fwd z-DFT via SGPR, passD z-inverse)
// 1152: szT [k*48+z]   384
// 1536: cxy [y*16+ki]  1024  (k_inv)
// 2560: sxy [y*16+ki]  1024
// 3584: cxyT[ki*64+y]  1024  (k_zy y-stage / k_xdft forward)
// 4608: sxyT[ki*64+y]  1024
__global__ void k_tables(float* tab){
    for(int idx=threadIdx.x; idx<384; idx+=blockDim.x){
        int z = idx>>3, k = idx&7;
        double a = 6.283185307179586476925286766559 * (double)((k*z)%48) / 48.0;
        float c = (float)cos(a), s = (float)sin(a);
        tab[idx]=c; tab[384+idx]=s;
        tab[768 + k*48+z]=c; tab[1152 + k*48+z]=s;
    }
    for(int idx=threadIdx.x; idx<1024; idx+=blockDim.x){
        int y = idx>>4, ki = idx&15;
        int ka = ki<8 ? ki : ki+48;
        double a = 6.283185307179586476925286766559 * (double)((ka*y)%64) / 64.0;
        float c=(float)cos(a), s=(float)sin(a);
        tab[1536+idx]=c; tab[2560+idx]=s;
        tab[3584 + ki*64+y]=c; tab[4608 + ki*64+y]=s;
    }
}

// ---------------- lifting: global-direct, SGPR weights ----------------
__global__ void __launch_bounds__(256) k_lift(const float* __restrict__ x,
                       const float* __restrict__ pw, const float* __restrict__ pb,
                       float* __restrict__ h){
    int t = blockIdx.x*256 + threadIdx.x;      // 393216 total
    int b = (t>=SPAT) ? 1 : 0; int col = t - b*SPAT;
    int xy = col/48, z = col%48;
    const float4* xp = (const float4*)(x + (size_t)t*40);
    float in[40];
    #pragma unroll
    for(int q=0;q<10;q++){
        float4 v = xp[q];
        in[q*4]=v.x; in[q*4+1]=v.y; in[q*4+2]=v.z; in[q*4+3]=v.w;
    }
    float gx = (float)(xy>>6)*(1.0f/63.0f);
    float gy = (float)(xy&63)*(1.0f/63.0f);
    float gz = (float)z*(1.0f/47.0f);
    for(int g=0;g<4;g++){
        const float* w = pw + g*260;
        #pragma unroll 4
        for(int c=0;c<20;c++){
            float a = pb[g*20+c];
            #pragma unroll
            for(int j=0;j<10;j++) a += in[g*10+j]*w[j*20+c];
            a += gx*w[200+c] + gy*w[220+c] + gz*w[240+c];
            h[(size_t)(b*80+g*20+c)*SPAT + col] = a;
        }
    }
}

// ---------------- fused forward z+y DFT + stats partials ----------------
// grid = ng*2b*20d*64x, 256 threads
__global__ void __launch_bounds__(256) k_zy(const float* __restrict__ h,
        float* __restrict__ ybuf, float* __restrict__ partZY,
        const float* __restrict__ tab, int gA,int gB,int gC,int gD){
    __shared__ __align__(16) float hl[64*52];   // [y][z] stride 52 (tiles banks for b128)
    __shared__ float sp[16*65];                 // [k*2+ri][y] stride 65
    __shared__ float cyl[16*65], syl[16*65];    // [ky][y] stride 65
    __shared__ float sred[8];
    int blk = blockIdx.x;
    int x = blk&63; int d=(blk>>6)%20; int r2 = blk/1280; int b = r2&1; int gi = r2>>1;
    int gl4[4]={gA,gB,gC,gD};
    int g = gl4[gi];
    int ch = g*20+d;
    int tid=threadIdx.x;
    const float4* src = (const float4*)(h + (size_t)(b*80+ch)*SPAT + (size_t)x*3072);
    float s1=0,s2=0;
    #pragma unroll
    for(int u=0;u<3;u++){
        int e=tid+u*256; float4 v=src[e];
        int y=e/12, zq=e%12;
        *(float4*)(hl + y*52 + zq*4) = v;
        s1 += v.x+v.y+v.z+v.w; s2 += v.x*v.x+v.y*v.y+v.z*v.z+v.w*v.w;
    }
    for(int tt=tid;tt<1024;tt+=256){
        int ki=tt>>6, y=tt&63;
        cyl[ki*65+y]=tab[3584+tt]; syl[ki*65+y]=tab[4608+tt];
    }
    s1=wred(s1); s2=wred(s2);
    if((tid&63)==0){ sred[(tid>>6)*2]=s1; sred[(tid>>6)*2+1]=s2; }
    __syncthreads();
    if(tid==0){
        size_t pi = ((size_t)(b*80+ch)*64+x)*2;
        partZY[pi]   = sred[0]+sred[2]+sred[4]+sred[6];
        partZY[pi+1] = sred[1]+sred[3]+sred[5]+sred[7];
    }
    // z-DFT: thread (y, kq), k = kq*2+kk; twiddles wave-uniform -> SGPR
    {
        int y = tid&63; int kq = tid>>6;
        float v[48];
        const float4* hr4 = (const float4*)(hl + y*52);
        #pragma unroll
        for(int q=0;q<12;q++){
            float4 t4=hr4[q];
            v[q*4]=t4.x; v[q*4+1]=t4.y; v[q*4+2]=t4.z; v[q*4+3]=t4.w;
        }
        #pragma unroll
        for(int kk=0;kk<2;kk++){
            int k = kq*2+kk;
            const float* CZ = tab+768+k*48;
            const float* SZ = tab+1152+k*48;
            float rr=0, si=0;
            #pragma unroll
            for(int z=0;z<48;z++){ rr += v[z]*CZ[z]; si += v[z]*SZ[z]; }
            sp[(k*2)*65+y]=rr; sp[(k*2+1)*65+y]=-si;
        }
    }
    __syncthreads();
    // y-DFT: 128 tasks (ky,kz)
    if(tid<128){
        int ky=tid>>3, kz=tid&7;
        const float* cy = cyl+ky*65; const float* sy = syl+ky*65;
        const float* spr = sp + (kz*2)*65;
        const float* spi = sp + (kz*2+1)*65;
        float fr=0, fi=0;
        #pragma unroll 8
        for(int y=0;y<64;y++){
            float sr=spr[y], si=spi[y];
            float c=cy[y], s=sy[y];
            fr += sr*c + si*s;
            fi += si*c - sr*s;
        }
        size_t base = ((size_t)((g*2+b)*20+d)*16 + ky)*1024 + (size_t)(kz*128);
        ybuf[base + x]      = fr;
        ybuf[base + 64 + x] = fi;
    }
}

// ---------------- forward x-DFT + norm1 fold -> per-channel cache ----------------
// grid = ng*2b*20d*16ky, 128 threads
__global__ void __launch_bounds__(128) k_xdft(const float* __restrict__ ybuf,
        float* __restrict__ fbufC, const float* __restrict__ partZY,
        const float* __restrict__ tab, int gA,int gB,int gC,int gD){
    __shared__ __align__(16) float ylx[16*68];  // [kz*2+ri][x] stride 68
    __shared__ float cxl[16*65], sxl[16*65];
    __shared__ float scs[1];
    int blk = blockIdx.x;
    int kyi = blk&15; int d=(blk>>4)%20; int r2=blk/320; int b=r2&1; int gi=r2>>1;
    int gl4[4]={gA,gB,gC,gD};
    int g=gl4[gi]; int ch=g*20+d;
    int tid=threadIdx.x;
    const float4* src = (const float4*)(ybuf + (((size_t)((g*2+b)*20+d)*16+kyi)*1024));
    #pragma unroll
    for(int u=0;u<2;u++){
        int e=tid+u*128; float4 v=src[e];
        int kzri = e>>4; int xx=(e&15)*4;
        *(float4*)(ylx + kzri*68 + xx) = v;
    }
    for(int tt=tid;tt<1024;tt+=128){
        int ki=tt>>6, y=tt&63;
        cxl[ki*65+y]=tab[3584+tt]; sxl[ki*65+y]=tab[4608+tt];
    }
    float s1=0,s2=0;
    if(tid<64){
        size_t pi=((size_t)(b*80+ch)*64+tid)*2;
        s1=partZY[pi]; s2=partZY[pi+1];
    }
    s1=wred(s1); s2=wred(s2);
    if(tid==0){
        float mean=s1*(1.0f/196608.0f);
        float var=s2*(1.0f/196608.0f)-mean*mean;
        scs[0]=rsqrtf(var+EPSV);
    }
    __syncthreads();
    float sc = scs[0];
    int kxi=tid>>3, kz=tid&7;
    const float* yr = ylx + (kz*2)*68;
    const float* yi = ylx + (kz*2+1)*68;
    const float* cx = cxl + kxi*65;
    const float* sx = sxl + kxi*65;
    float fr=0, fi=0;
    #pragma unroll 8
    for(int xx=0;xx<64;xx++){
        float a=yr[xx], e2=yi[xx];
        float c=cx[xx], s=sx[xx];
        fr += a*c + e2*s;
        fi += e2*c - a*s;
    }
    fr*=sc; fi*=sc;
    if(kxi==0 && kyi==0 && kz==0){ fr=0.0f; fi=0.0f; }
    size_t idx = ((size_t)(b*80+ch)*2048 + (size_t)((kxi*16+kyi)*8+kz))*2;
    fbufC[idx]=fr; fbufC[idx+1]=fi;
}

// ---------------- residual conv (global-direct, SGPR weights) ----------------
__global__ void __launch_bounds__(256) k_res(const float* __restrict__ h,
        const float* __restrict__ ww, const float* __restrict__ wb,
        float* __restrict__ rbuf, int li, int g0, int g1, int g2){
    int t = blockIdx.x*256 + threadIdx.x;      // 98304 total
    int b = t/49152; int r = t - b*49152; int xy = r/12; int zq = r%12;
    const float* W = ww + li*1600;
    float4 acc[20];
    #pragma unroll
    for(int o=0;o<20;o++){ float bv = wb[li*20+o]; acc[o]=make_float4(bv,bv,bv,bv); }
    size_t sp = (size_t)xy*48 + zq*4;
    const float* h0 = h + ((size_t)(b*80+g0*20))*SPAT + sp;
    const float* h1 = h + ((size_t)(b*80+g1*20))*SPAT + sp;
    const float* h2 = h + ((size_t)(b*80+g2*20))*SPAT + sp;
    for(int c=0;c<20;c++){
        float4 v = *(const float4*)(h0 + (size_t)c*SPAT);
        #pragma unroll
        for(int o=0;o<20;o++){
            float w = W[o*80+c] + W[o*80+20+c];
            acc[o].x += w*v.x; acc[o].y += w*v.y; acc[o].z += w*v.z; acc[o].w += w*v.w;
        }
    }
    for(int c=0;c<20;c++){
        float4 v = *(const float4*)(h1 + (size_t)c*SPAT);
        #pragma unroll
        for(int o=0;o<20;o++){
            float w = W[o*80+40+c];
            acc[o].x += w*v.x; acc[o].y += w*v.y; acc[o].z += w*v.z; acc[o].w += w*v.w;
        }
    }
    for(int c=0;c<20;c++){
        float4 v = *(const float4*)(h2 + (size_t)c*SPAT);
        #pragma unroll
        for(int o=0;o<20;o++){
            float w = W[o*80+60+c];
            acc[o].x += w*v.x; acc[o].y += w*v.y; acc[o].z += w*v.z; acc[o].w += w*v.w;
        }
    }
    #pragma unroll
    for(int o=0;o<20;o++)
        *(float4*)(rbuf + ((size_t)(b*20+o))*SPAT + sp) = acc[o];
}

// ---------------- spectral multiply (reads per-channel cache) ----------------
__global__ void k_spec(const float* __restrict__ fbufC, const float* __restrict__ sw,
                       float* __restrict__ gbuf, float* __restrict__ stat2,
                       int li, int g0, int g1, int g2){
    int blk = blockIdx.x;
    int m1p = blk & 3, o = (blk>>2)%20, q = blk/80;
    if(q==0 && m1p==0 && threadIdx.x<2){
        int b = threadIdx.x;
        stat2[(b*20+o)*2]=0.f; stat2[(b*20+o)*2+1]=0.f;
    }
    int offx = (q&1)*8, offy = (q>>1)*8;
    int t = threadIdx.x;
    int m1 = m1p*2 + (t>>5);
    int m2 = (t>>2)&7;
    int m3 = (t&3)*2;
    int tw = m1*64 + m2*8 + m3;
    int kxi = m1+offx, kyi = m2+offy;
    int fo = (kxi*16 + kyi)*8 + m3;   // even
    const float4* wp = (const float4*)(sw + (((size_t)(li*4+q)*1600) + o)*1024 + (size_t)tw*2);
    const float4* fb = (const float4*)fbufC + (fo>>1);
    float r00=0,i00=0,r01=0,i01=0, r10=0,i10=0,r11=0,i11=0;
    #pragma unroll 4
    for(int c=0;c<20;c++){
        float4 wa = wp[(size_t)c*5120];
        float4 wb4= wp[(size_t)(c+20)*5120];
        float wr0 = wa.x + wb4.x, wi0 = wa.y + wb4.y, wr1 = wa.z + wb4.z, wi1 = wa.w + wb4.w;
        float4 f0 = fb[(size_t)(g0*20+c)*1024];
        float4 f1 = fb[(size_t)(80+g0*20+c)*1024];
        r00 += f0.x*wr0 - f0.y*wi0; i00 += f0.x*wi0 + f0.y*wr0;
        r01 += f0.z*wr1 - f0.w*wi1; i01 += f0.z*wi1 + f0.w*wr1;
        r10 += f1.x*wr0 - f1.y*wi0; i10 += f1.x*wi0 + f1.y*wr0;
        r11 += f1.z*wr1 - f1.w*wi1; i11 += f1.z*wi1 + f1.w*wr1;
    }
    #pragma unroll 4
    for(int c=0;c<20;c++){
        float4 wa = wp[(size_t)(c+40)*5120];
        float4 f0 = fb[(size_t)(g1*20+c)*1024];
        float4 f1 = fb[(size_t)(80+g1*20+c)*1024];
        r00 += f0.x*wa.x - f0.y*wa.y; i00 += f0.x*wa.y + f0.y*wa.x;
        r01 += f0.z*wa.z - f0.w*wa.w; i01 += f0.z*wa.w + f0.w*wa.z;
        r10 += f1.x*wa.x - f1.y*wa.y; i10 += f1.x*wa.y + f1.y*wa.x;
        r11 += f1.z*wa.z - f1.w*wa.w; i11 += f1.z*wa.w + f1.w*wa.z;
    }
    #pragma unroll 4
    for(int c=0;c<20;c++){
        float4 wa = wp[(size_t)(c+60)*5120];
        float4 f0 = fb[(size_t)(g2*20+c)*1024];
        float4 f1 = fb[(size_t)(80+g2*20+c)*1024];
        r00 += f0.x*wa.x - f0.y*wa.y; i00 += f0.x*wa.y + f0.y*wa.x;
        r01 += f0.z*wa.z - f0.w*wa.w; i01 += f0.z*wa.w + f0.w*wa.z;
        r10 += f1.x*wa.x - f1.y*wa.y; i10 += f1.x*wa.y + f1.y*wa.x;
        r11 += f1.z*wa.z - f1.w*wa.w; i11 += f1.z*wa.w + f1.w*wa.z;
    }
    float4* gg0 = (float4*)(gbuf + (size_t)o*4096 + fo*2);
    float4* gg1 = (float4*)(gbuf + (size_t)(20+o)*4096 + fo*2);
    *gg0 = make_float4(r00,i00,r01,i01);
    *gg1 = make_float4(r10,i10,r11,i11);
}

// ---------------- fused inverse x + y (+ Parseval stats for norm2) ----------------
__global__ void k_inv(const float* __restrict__ gbuf, float* __restrict__ iybuf,
                      float* __restrict__ stat2, const float* __restrict__ tab){
    __shared__ __align__(16) float gl[4096];
    __shared__ float tmp[256];
    __shared__ float cl[1088], sl[1088];   // [y][ki] stride 17
    __shared__ float ig[4];
    int blk = blockIdx.x;
    int nx = blk&63, o = (blk>>6)%20, b = blk/1280;
    const float4* src4 = (const float4*)(gbuf + (size_t)(b*20+o)*4096);
    for(int t=threadIdx.x;t<1024;t+=blockDim.x) ((float4*)gl)[t]=src4[t];
    for(int t=threadIdx.x;t<1024;t+=blockDim.x){
        int y=t>>4, ki=t&15;
        cl[y*17+ki]=tab[1536+t]; sl[y*17+ki]=tab[2560+t];
    }
    __syncthreads();
    {
        int kyi = threadIdx.x>>3, kz = threadIdx.x&7;
        float ar=0, ai=0;
        #pragma unroll 4
        for(int kxi=0;kxi<16;kxi++){
            float gr = gl[((kxi*16+kyi)*8+kz)*2], gi2 = gl[((kxi*16+kyi)*8+kz)*2+1];
            float c = cl[nx*17+kxi], s = sl[nx*17+kxi];
            ar += gr*c - gi2*s;
            ai += gi2*c + gr*s;
        }
        tmp[threadIdx.x*2]   = ar*(1.0f/64.0f);
        tmp[threadIdx.x*2+1] = ai*(1.0f/64.0f);
    }
    __syncthreads();
    float p1=0,p2=0;
    for(int j=0;j<4;j++){
        int out = threadIdx.x + j*128;
        int ny = out>>3, kz = out&7;
        float ar=0, ai=0;
        #pragma unroll 4
        for(int kyi=0;kyi<16;kyi++){
            float vr = tmp[(kyi*8+kz)*2], vi = tmp[(kyi*8+kz)*2+1];
            float c = cl[ny*17+kyi], s = sl[ny*17+kyi];
            ar += vr*c - vi*s;
            ai += vi*c + vr*s;
        }
        ar *= (1.0f/64.0f); ai *= (1.0f/64.0f);
        size_t idx = ((((size_t)(b*20+o)*64+nx)*64+ny)*8+kz)*2;
        iybuf[idx]=ar; iybuf[idx+1]=ai;
        if(kz==0){ p1 += ar; p2 += ar*ar; }
        else p2 += 2.0f*(ar*ar+ai*ai);
    }
    p2 *= (1.0f/48.0f);
    float r1=wred(p1), r2=wred(p2);
    int wv = threadIdx.x>>6;
    if((threadIdx.x&63)==0){ ig[wv*2]=r1; ig[wv*2+1]=r2; }
    __syncthreads();
    if(threadIdx.x==0){
        atomicAdd(&stat2[(b*20+o)*2],   ig[0]+ig[2]);
        atomicAdd(&stat2[(b*20+o)*2+1], ig[1]+ig[3]);
    }
}

// ---------------- pass D: z-inverse + norm2 + MLP + residual add + h write ----------------
__global__ void __launch_bounds__(256) k_passD(
        const float* __restrict__ iybuf, const float* __restrict__ rbuf,
        const float* __restrict__ w1, const float* __restrict__ b1,
        const float* __restrict__ w2, const float* __restrict__ b2,
        float* __restrict__ h,
        const float* __restrict__ stat2, const float* __restrict__ tab,
        int li, int grp){
    __shared__ __align__(16) float dl[2560];
    __shared__ __align__(16) float vl[20*392];
    __shared__ float m2l[20], s2l[20];
    __shared__ float czl[384], szl[384];
    int blk = blockIdx.x;
    int nyt = blk&7, nx=(blk>>3)&63, b = blk>>9;
    int tid = threadIdx.x;
    for(int u=tid; u<640; u+=256){
        int o = u>>5, j = u&31;
        const float4* s4 = (const float4*)(iybuf + ((((size_t)(b*20+o)*64+nx)*64 + nyt*8)*16));
        ((float4*)dl)[o*32+j] = s4[j];
    }
    if(tid<20){
        float S1 = stat2[(b*20+tid)*2], S2 = stat2[(b*20+tid)*2+1];
        float mean = S1*(1.0f/196608.0f);
        float var = S2*(1.0f/196608.0f) - mean*mean;
        m2l[tid]=mean; s2l[tid]=rsqrtf(var+EPSV);
    }
    for(int t=tid;t<384;t+=256){ czl[t]=tab[768+t]; szl[t]=tab[1152+t]; }
    __syncthreads();
    for(int idx=tid; idx<7680; idx+=256){
        int o = idx/384, p = idx%384;
        int ny = p/48, nz = p%48;
        const float* dd = dl + o*128 + ny*16;
        float acc = dd[0];
        #pragma unroll
        for(int k=1;k<8;k++)
            acc += 2.0f*(dd[k*2]*czl[k*48+nz] - dd[k*2+1]*szl[k*48+nz]);
        float xv = acc*(1.0f/48.0f);
        vl[o*392+p] = (xv - m2l[o])*s2l[o];
    }
    __syncthreads();
    const float* W1 = w1 + li*400;
    const float* W2 = w2 + li*400;
    const float* B1 = b1 + li*20;
    const float* B2 = b2 + li*20;
    for(int p=tid; p<384; p+=256){
        float vj[20], t1[20];
        #pragma unroll
        for(int j2=0;j2<20;j2++) vj[j2]=vl[j2*392+p];
        #pragma unroll
        for(int oo=0;oo<20;oo++){
            float a = B1[oo];
            #pragma unroll
            for(int j2=0;j2<20;j2++) a += vj[j2]*W1[oo*20+j2];
            t1[oo] = geluf(a);
        }
        #pragma unroll
        for(int oo=0;oo<20;oo++){
            float a = B2[oo];
            #pragma unroll
            for(int j2=0;j2<20;j2++) a += t1[j2]*W2[oo*20+j2];
            vl[oo*392+p] = a;
        }
    }
    __syncthreads();
    int sb = (nx*64 + nyt*8)*48;
    if(tid<240){
        int o = tid/12, s = tid%12;
        const float4* vo4 = (const float4*)(vl + o*392);
        const float4* rb4 = (const float4*)(rbuf + (size_t)(b*20+o)*SPAT + sb);
        float4* hp4 = (float4*)(h + (size_t)(b*80+grp*20+o)*SPAT + sb);
        #pragma unroll
        for(int j=0;j<8;j++){
            int qq = s + j*12;
            float4 v = vo4[qq], r = rb4[qq];
            v.x+=r.x; v.y+=r.y; v.z+=r.z; v.w+=r.w;
            hp4[qq]=v;
        }
    }
}

// ---------------- layer-end gelu (in place) ----------------
__global__ void k_gelu(float* __restrict__ h){
    int blk = blockIdx.x;
    size_t base = (size_t)blk*4096;
    float4* hp = (float4*)(h+base);
    for(int e=threadIdx.x;e<1024;e+=blockDim.x){
        float4 v = hp[e];
        v.x=geluf(v.x); v.y=geluf(v.y); v.z=geluf(v.z); v.w=geluf(v.w);
        hp[e]=v;
    }
}

// ---------------- output head (register MLP, SGPR weights, 4x parallel) ----------------
__global__ void __launch_bounds__(256) k_head(const float* __restrict__ h,
        const float* __restrict__ qw1, const float* __restrict__ qb1,
        const float* __restrict__ qw2, const float* __restrict__ qb2,
        float* __restrict__ out){
    int g = blockIdx.x & 3;
    int t = (blockIdx.x>>2)*256 + threadIdx.x;   // 0..393215
    int b = (t>=SPAT) ? 1 : 0; int col = t - b*SPAT;
    const float* hb = h + (size_t)(b*80+g*20)*SPAT + col;
    float in20[20];
    #pragma unroll
    for(int j=0;j<20;j++) in20[j] = hb[(size_t)j*SPAT];
    float o20[20];
    #pragma unroll
    for(int o2=0;o2<20;o2++) o20[o2] = qb2[g*20+o2];
    for(int o8=0;o8<80;o8++){
        float a = qb1[g*80+o8];
        #pragma unroll
        for(int j=0;j<20;j++) a += in20[j]*qw1[g*1600 + o8*20 + j];
        a = geluf(a);
        #pragma unroll
        for(int o2=0;o2<20;o2++) o20[o2] += a*qw2[g*1600 + o2*80 + o8];
    }
    float* op = out + (size_t)t*80 + g*20;
    #pragma unroll
    for(int q=0;q<5;q++)
        *(float4*)(op + q*4) = make_float4(o20[q*4],o20[q*4+1],o20[q*4+2],o20[q*4+3]);
}

extern "C" void kernel_launch(void* const* d_in, const int* in_sizes, int n_in,
                              void* d_out, int out_size, void* d_ws, size_t ws_size,
                              hipStream_t stream){
    (void)in_sizes; (void)n_in; (void)out_size;
    const float* x    = (const float*)d_in[0];
    const float* p_w  = (const float*)d_in[1];
    const float* p_b  = (const float*)d_in[2];
    const float* spec = (const float*)d_in[3];
    const float* w1   = (const float*)d_in[4];
    const float* b1   = (const float*)d_in[5];
    const float* w2   = (const float*)d_in[6];
    const float* b2   = (const float*)d_in[7];
    const float* ww   = (const float*)d_in[8];
    const float* wb   = (const float*)d_in[9];
    const float* qw1  = (const float*)d_in[10];
    const float* qb1  = (const float*)d_in[11];
    const float* qw2  = (const float*)d_in[12];
    const float* qb2  = (const float*)d_in[13];
    float* out = (float*)d_out;
    float* ws  = (float*)d_ws;

    if(ws_size < (size_t)45409872*4) return;  // ~182 MB scratch

    float* h      = ws;                       // 31,457,280
    float* rbuf   = ws + 31457280;            //  7,864,320
    float* ybuf   = ws + 39321600;            //  2,621,440
    float* gbuf   = ws + 41943040;            //    163,840
    float* iyb    = ws + 42106880;            //  2,621,440
    float* fbufC  = ws + 44728320;            //    655,360
    float* partZY = ws + 45383680;            //     20,480
    float* stat2  = ws + 45404160;            //         80
    float* tab    = ws + 45404240;            //      5,632

    k_tables<<<1,256,0,stream>>>(tab);
    k_lift<<<1536,256,0,stream>>>(x, p_w, p_b, h);

    static const int ORD3[4][3] = {{0,1,2},{1,2,3},{2,3,0},{3,0,1}};
    for(int l=0;l<4;l++){
        for(int bi=0;bi<2;bi++){
            if(bi==0){
                // all 4 groups, pre-layer h (iters 0 and 1 both read only pre-layer channels)
                k_zy  <<<10240,256,0,stream>>>(h, ybuf, partZY, tab, 0,1,2,3);
                k_xdft<<< 2560,128,0,stream>>>(ybuf, fbufC, partZY, tab, 0,1,2,3);
            } else {
                // groups 0,1 were updated by iters 0,1; groups 2,3 caches still valid
                k_zy  <<< 5120,256,0,stream>>>(h, ybuf, partZY, tab, 0,1,0,0);
                k_xdft<<< 1280,128,0,stream>>>(ybuf, fbufC, partZY, tab, 0,1,0,0);
            }
            for(int ii=0;ii<2;ii++){
                int i = bi*2+ii; int li = l*4+i;
                int g0=ORD3[i][0], g1=ORD3[i][1], g2=ORD3[i][2];
                k_res  <<< 384,256,0,stream>>>(h, ww, wb, rbuf, li, g0,g1,g2);
                k_spec <<< 320, 64,0,stream>>>(fbufC, spec, gbuf, stat2, li, g0,g1,g2);
                k_inv  <<<2560,128,0,stream>>>(gbuf, iyb, stat2, tab);
                k_passD<<<1024,256,0,stream>>>(iyb, rbuf, w1, b1, w2, b2, h, stat2, tab, li, i);
            }
        }
        if(l<3) k_gelu<<<7680,256,0,stream>>>(h);
    }
    k_head<<<6144,256,0,stream>>>(h, qw1, qb1, qw2, qb2, out);
}

// Round 6
// 3379.433 us; speedup vs baseline: 6.3401x; 1.0553x over previous
//
#include <hip/hip_runtime.h>
#include <math.h>

#define SPAT 196608   // 64*64*48
#define EPSV 1e-5f

__device__ __forceinline__ float geluf(float x){
    return 0.5f*x*(1.0f + erff(x*0.70710678118654752440f));
}
__device__ __forceinline__ float wred(float v){
    #pragma unroll
    for(int o=32;o>0;o>>=1) v += __shfl_down(v,o);
    return v;
}

// ---------------- twiddle tables ----------------
// 768:  czT [k*48+z]   384   (k_zy fwd z-DFT via SGPR, passD z-inverse)
// 1152: szT [k*48+z]   384
// 1536: cxy [y*16+ki]  1024  (k_inv)
// 2560: sxy [y*16+ki]  1024
// 3584: cxyT[ki*64+y]  1024  (k_zy y-stage / k_xdft forward)
// 4608: sxyT[ki*64+y]  1024
__global__ void k_tables(float* tab){
    for(int idx=threadIdx.x; idx<384; idx+=blockDim.x){
        int z = idx>>3, k = idx&7;
        double a = 6.283185307179586476925286766559 * (double)((k*z)%48) / 48.0;
        float c = (float)cos(a), s = (float)sin(a);
        tab[idx]=c; tab[384+idx]=s;
        tab[768 + k*48+z]=c; tab[1152 + k*48+z]=s;
    }
    for(int idx=threadIdx.x; idx<1024; idx+=blockDim.x){
        int y = idx>>4, ki = idx&15;
        int ka = ki<8 ? ki : ki+48;
        double a = 6.283185307179586476925286766559 * (double)((ka*y)%64) / 64.0;
        float c=(float)cos(a), s=(float)sin(a);
        tab[1536+idx]=c; tab[2560+idx]=s;
        tab[3584 + ki*64+y]=c; tab[4608 + ki*64+y]=s;
    }
}

// ---------------- lifting: global-direct, SGPR weights ----------------
__global__ void __launch_bounds__(256) k_lift(const float* __restrict__ x,
                       const float* __restrict__ pw, const float* __restrict__ pb,
                       float* __restrict__ h){
    int t = blockIdx.x*256 + threadIdx.x;      // 393216 total
    int b = (t>=SPAT) ? 1 : 0; int col = t - b*SPAT;
    int xy = col/48, z = col%48;
    const float4* xp = (const float4*)(x + (size_t)t*40);
    float in[40];
    #pragma unroll
    for(int q=0;q<10;q++){
        float4 v = xp[q];
        in[q*4]=v.x; in[q*4+1]=v.y; in[q*4+2]=v.z; in[q*4+3]=v.w;
    }
    float gx = (float)(xy>>6)*(1.0f/63.0f);
    float gy = (float)(xy&63)*(1.0f/63.0f);
    float gz = (float)z*(1.0f/47.0f);
    for(int g=0;g<4;g++){
        const float* w = pw + g*260;
        #pragma unroll 4
        for(int c=0;c<20;c++){
            float a = pb[g*20+c];
            #pragma unroll
            for(int j=0;j<10;j++) a += in[g*10+j]*w[j*20+c];
            a += gx*w[200+c] + gy*w[220+c] + gz*w[240+c];
            h[(size_t)(b*80+g*20+c)*SPAT + col] = a;
        }
    }
}

// ---------------- fused forward z+y DFT + stats partials ----------------
__global__ void __launch_bounds__(256) k_zy(const float* __restrict__ h,
        float* __restrict__ ybuf, float* __restrict__ partZY,
        const float* __restrict__ tab, int gA,int gB,int gC,int gD){
    __shared__ __align__(16) float hl[64*52];   // [y][z] stride 52
    __shared__ float sp[16*65];                 // [k*2+ri][y] stride 65
    __shared__ float cyl[16*65], syl[16*65];    // [ky][y] stride 65
    __shared__ float sred[8];
    int blk = blockIdx.x;
    int x = blk&63; int d=(blk>>6)%20; int r2 = blk/1280; int b = r2&1; int gi = r2>>1;
    int gl4[4]={gA,gB,gC,gD};
    int g = gl4[gi];
    int ch = g*20+d;
    int tid=threadIdx.x;
    const float4* src = (const float4*)(h + (size_t)(b*80+ch)*SPAT + (size_t)x*3072);
    float s1=0,s2=0;
    #pragma unroll
    for(int u=0;u<3;u++){
        int e=tid+u*256; float4 v=src[e];
        int y=e/12, zq=e%12;
        *(float4*)(hl + y*52 + zq*4) = v;
        s1 += v.x+v.y+v.z+v.w; s2 += v.x*v.x+v.y*v.y+v.z*v.z+v.w*v.w;
    }
    for(int tt=tid;tt<1024;tt+=256){
        int ki=tt>>6, y=tt&63;
        cyl[ki*65+y]=tab[3584+tt]; syl[ki*65+y]=tab[4608+tt];
    }
    s1=wred(s1); s2=wred(s2);
    if((tid&63)==0){ sred[(tid>>6)*2]=s1; sred[(tid>>6)*2+1]=s2; }
    __syncthreads();
    if(tid==0){
        size_t pi = ((size_t)(b*80+ch)*64+x)*2;
        partZY[pi]   = sred[0]+sred[2]+sred[4]+sred[6];
        partZY[pi+1] = sred[1]+sred[3]+sred[5]+sred[7];
    }
    {
        int y = tid&63; int kq = tid>>6;
        float v[48];
        const float4* hr4 = (const float4*)(hl + y*52);
        #pragma unroll
        for(int q=0;q<12;q++){
            float4 t4=hr4[q];
            v[q*4]=t4.x; v[q*4+1]=t4.y; v[q*4+2]=t4.z; v[q*4+3]=t4.w;
        }
        #pragma unroll
        for(int kk=0;kk<2;kk++){
            int k = kq*2+kk;
            const float* CZ = tab+768+k*48;
            const float* SZ = tab+1152+k*48;
            float rr=0, si=0;
            #pragma unroll
            for(int z=0;z<48;z++){ rr += v[z]*CZ[z]; si += v[z]*SZ[z]; }
            sp[(k*2)*65+y]=rr; sp[(k*2+1)*65+y]=-si;
        }
    }
    __syncthreads();
    if(tid<128){
        int ky=tid>>3, kz=tid&7;
        const float* cy = cyl+ky*65; const float* sy = syl+ky*65;
        const float* spr = sp + (kz*2)*65;
        const float* spi = sp + (kz*2+1)*65;
        float fr=0, fi=0;
        #pragma unroll 8
        for(int y=0;y<64;y++){
            float sr=spr[y], si=spi[y];
            float c=cy[y], s=sy[y];
            fr += sr*c + si*s;
            fi += si*c - sr*s;
        }
        size_t base = ((size_t)((g*2+b)*20+d)*16 + ky)*1024 + (size_t)(kz*128);
        ybuf[base + x]      = fr;
        ybuf[base + 64 + x] = fi;
    }
}

// ---------------- forward x-DFT + norm1 fold -> per-channel cache ----------------
__global__ void __launch_bounds__(128) k_xdft(const float* __restrict__ ybuf,
        float* __restrict__ fbufC, const float* __restrict__ partZY,
        const float* __restrict__ tab, int gA,int gB,int gC,int gD){
    __shared__ __align__(16) float ylx[16*68];  // [kz*2+ri][x] stride 68
    __shared__ float cxl[16*65], sxl[16*65];
    __shared__ float scs[1];
    int blk = blockIdx.x;
    int kyi = blk&15; int d=(blk>>4)%20; int r2=blk/320; int b=r2&1; int gi=r2>>1;
    int gl4[4]={gA,gB,gC,gD};
    int g=gl4[gi]; int ch=g*20+d;
    int tid=threadIdx.x;
    const float4* src = (const float4*)(ybuf + (((size_t)((g*2+b)*20+d)*16+kyi)*1024));
    #pragma unroll
    for(int u=0;u<2;u++){
        int e=tid+u*128; float4 v=src[e];
        int kzri = e>>4; int xx=(e&15)*4;
        *(float4*)(ylx + kzri*68 + xx) = v;
    }
    for(int tt=tid;tt<1024;tt+=128){
        int ki=tt>>6, y=tt&63;
        cxl[ki*65+y]=tab[3584+tt]; sxl[ki*65+y]=tab[4608+tt];
    }
    float s1=0,s2=0;
    if(tid<64){
        size_t pi=((size_t)(b*80+ch)*64+tid)*2;
        s1=partZY[pi]; s2=partZY[pi+1];
    }
    s1=wred(s1); s2=wred(s2);
    if(tid==0){
        float mean=s1*(1.0f/196608.0f);
        float var=s2*(1.0f/196608.0f)-mean*mean;
        scs[0]=rsqrtf(var+EPSV);
    }
    __syncthreads();
    float sc = scs[0];
    int kxi=tid>>3, kz=tid&7;
    const float* yr = ylx + (kz*2)*68;
    const float* yi = ylx + (kz*2+1)*68;
    const float* cx = cxl + kxi*65;
    const float* sx = sxl + kxi*65;
    float fr=0, fi=0;
    #pragma unroll 8
    for(int xx=0;xx<64;xx++){
        float a=yr[xx], e2=yi[xx];
        float c=cx[xx], s=sx[xx];
        fr += a*c + e2*s;
        fi += e2*c - a*s;
    }
    fr*=sc; fi*=sc;
    if(kxi==0 && kyi==0 && kz==0){ fr=0.0f; fi=0.0f; }
    size_t idx = ((size_t)(b*80+ch)*2048 + (size_t)((kxi*16+kyi)*8+kz))*2;
    fbufC[idx]=fr; fbufC[idx+1]=fi;
}

// ---------------- spectral multiply: 256 threads, 4-way c-split ----------------
__global__ void __launch_bounds__(256) k_spec(const float* __restrict__ fbufC,
        const float* __restrict__ sw, float* __restrict__ gbuf,
        float* __restrict__ stat2, int li, int g0, int g1, int g2){
    __shared__ float part[2112];
    int blk = blockIdx.x;
    int m1p = blk & 3, o = (blk>>2)%20, q = blk/80;
    int tid = threadIdx.x;
    int t64 = tid & 63, cc = tid >> 6;
    if(q==0 && m1p==0 && tid<2){
        stat2[(tid*20+o)*2]=0.f; stat2[(tid*20+o)*2+1]=0.f;
    }
    int offx = (q&1)*8, offy = (q>>1)*8;
    int m1 = m1p*2 + (t64>>5);
    int m2 = (t64>>2)&7;
    int m3 = (t64&3)*2;
    int tw = m1*64 + m2*8 + m3;
    int kxi = m1+offx, kyi = m2+offy;
    int fo = (kxi*16 + kyi)*8 + m3;   // even
    const float4* wp = (const float4*)(sw + (((size_t)(li*4+q)*1600) + o)*1024 + (size_t)tw*2);
    const float4* fb = (const float4*)fbufC + (fo>>1);
    float r00=0,i00=0,r01=0,i01=0, r10=0,i10=0,r11=0,i11=0;
    int c0 = cc*5;
    #pragma unroll
    for(int u=0;u<5;u++){
        int c = c0+u;
        float4 wa = wp[(size_t)c*5120];
        float4 wb4= wp[(size_t)(c+20)*5120];
        float wr0 = wa.x + wb4.x, wi0 = wa.y + wb4.y, wr1 = wa.z + wb4.z, wi1 = wa.w + wb4.w;
        float4 f0 = fb[(size_t)(g0*20+c)*1024];
        float4 f1 = fb[(size_t)(80+g0*20+c)*1024];
        r00 += f0.x*wr0 - f0.y*wi0; i00 += f0.x*wi0 + f0.y*wr0;
        r01 += f0.z*wr1 - f0.w*wi1; i01 += f0.z*wi1 + f0.w*wr1;
        r10 += f1.x*wr0 - f1.y*wi0; i10 += f1.x*wi0 + f1.y*wr0;
        r11 += f1.z*wr1 - f1.w*wi1; i11 += f1.z*wi1 + f1.w*wr1;
    }
    #pragma unroll
    for(int u=0;u<5;u++){
        int c = c0+u;
        float4 wa = wp[(size_t)(c+40)*5120];
        float4 f0 = fb[(size_t)(g1*20+c)*1024];
        float4 f1 = fb[(size_t)(80+g1*20+c)*1024];
        r00 += f0.x*wa.x - f0.y*wa.y; i00 += f0.x*wa.y + f0.y*wa.x;
        r01 += f0.z*wa.z - f0.w*wa.w; i01 += f0.z*wa.w + f0.w*wa.z;
        r10 += f1.x*wa.x - f1.y*wa.y; i10 += f1.x*wa.y + f1.y*wa.x;
        r11 += f1.z*wa.z - f1.w*wa.w; i11 += f1.z*wa.w + f1.w*wa.z;
    }
    #pragma unroll
    for(int u=0;u<5;u++){
        int c = c0+u;
        float4 wa = wp[(size_t)(c+60)*5120];
        float4 f0 = fb[(size_t)(g2*20+c)*1024];
        float4 f1 = fb[(size_t)(80+g2*20+c)*1024];
        r00 += f0.x*wa.x - f0.y*wa.y; i00 += f0.x*wa.y + f0.y*wa.x;
        r01 += f0.z*wa.z - f0.w*wa.w; i01 += f0.z*wa.w + f0.w*wa.z;
        r10 += f1.x*wa.x - f1.y*wa.y; i10 += f1.x*wa.y + f1.y*wa.x;
        r11 += f1.z*wa.z - f1.w*wa.w; i11 += f1.z*wa.w + f1.w*wa.z;
    }
    float vals[8]={r00,i00,r01,i01,r10,i10,r11,i11};
    #pragma unroll
    for(int e=0;e<8;e++) part[t64*33 + e*4 + cc] = vals[e];
    __syncthreads();
    if(cc==0){
        float acc[8];
        #pragma unroll
        for(int e=0;e<8;e++){
            const float* p = part + t64*33 + e*4;
            acc[e] = p[0]+p[1]+p[2]+p[3];
        }
        float4* gg0 = (float4*)(gbuf + (size_t)o*4096 + fo*2);
        float4* gg1 = (float4*)(gbuf + (size_t)(20+o)*4096 + fo*2);
        *gg0 = make_float4(acc[0],acc[1],acc[2],acc[3]);
        *gg1 = make_float4(acc[4],acc[5],acc[6],acc[7]);
    }
}

// ---------------- fused inverse x + y (+ Parseval stats for norm2) ----------------
__global__ void k_inv(const float* __restrict__ gbuf, float* __restrict__ iybuf,
                      float* __restrict__ stat2, const float* __restrict__ tab){
    __shared__ __align__(16) float gl[4096];
    __shared__ float tmp[256];
    __shared__ float cl[1088], sl[1088];   // [y][ki] stride 17
    __shared__ float ig[4];
    int blk = blockIdx.x;
    int nx = blk&63, o = (blk>>6)%20, b = blk/1280;
    const float4* src4 = (const float4*)(gbuf + (size_t)(b*20+o)*4096);
    for(int t=threadIdx.x;t<1024;t+=blockDim.x) ((float4*)gl)[t]=src4[t];
    for(int t=threadIdx.x;t<1024;t+=blockDim.x){
        int y=t>>4, ki=t&15;
        cl[y*17+ki]=tab[1536+t]; sl[y*17+ki]=tab[2560+t];
    }
    __syncthreads();
    {
        int kyi = threadIdx.x>>3, kz = threadIdx.x&7;
        float ar=0, ai=0;
        #pragma unroll 4
        for(int kxi=0;kxi<16;kxi++){
            float gr = gl[((kxi*16+kyi)*8+kz)*2], gi2 = gl[((kxi*16+kyi)*8+kz)*2+1];
            float c = cl[nx*17+kxi], s = sl[nx*17+kxi];
            ar += gr*c - gi2*s;
            ai += gi2*c + gr*s;
        }
        tmp[threadIdx.x*2]   = ar*(1.0f/64.0f);
        tmp[threadIdx.x*2+1] = ai*(1.0f/64.0f);
    }
    __syncthreads();
    float p1=0,p2=0;
    for(int j=0;j<4;j++){
        int out = threadIdx.x + j*128;
        int ny = out>>3, kz = out&7;
        float ar=0, ai=0;
        #pragma unroll 4
        for(int kyi=0;kyi<16;kyi++){
            float vr = tmp[(kyi*8+kz)*2], vi = tmp[(kyi*8+kz)*2+1];
            float c = cl[ny*17+kyi], s = sl[ny*17+kyi];
            ar += vr*c - vi*s;
            ai += vi*c + vr*s;
        }
        ar *= (1.0f/64.0f); ai *= (1.0f/64.0f);
        size_t idx = ((((size_t)(b*20+o)*64+nx)*64+ny)*8+kz)*2;
        iybuf[idx]=ar; iybuf[idx+1]=ai;
        if(kz==0){ p1 += ar; p2 += ar*ar; }
        else p2 += 2.0f*(ar*ar+ai*ai);
    }
    p2 *= (1.0f/48.0f);
    float r1=wred(p1), r2=wred(p2);
    int wv = threadIdx.x>>6;
    if((threadIdx.x&63)==0){ ig[wv*2]=r1; ig[wv*2+1]=r2; }
    __syncthreads();
    if(threadIdx.x==0){
        atomicAdd(&stat2[(b*20+o)*2],   ig[0]+ig[2]);
        atomicAdd(&stat2[(b*20+o)*2+1], ig[1]+ig[3]);
    }
}

// ---------------- pass D: z-inverse + norm2 + MLP + fused residual + h write ----------------
__global__ void __launch_bounds__(256) k_passD(
        const float* __restrict__ iybuf,
        const float* __restrict__ w1, const float* __restrict__ b1,
        const float* __restrict__ w2, const float* __restrict__ b2,
        const float* __restrict__ ww, const float* __restrict__ wb,
        float* __restrict__ h,
        const float* __restrict__ stat2, const float* __restrict__ tab,
        int li, int grp, int g1, int g2){
    __shared__ __align__(16) float dl[2560];
    __shared__ __align__(16) float vl[20*392];
    __shared__ float m2l[20], s2l[20];
    __shared__ float czl[384], szl[384];
    int blk = blockIdx.x;
    int nyt = blk&7, nx=(blk>>3)&63, b = blk>>9;
    int tid = threadIdx.x;
    for(int u=tid; u<640; u+=256){
        int o = u>>5, j = u&31;
        const float4* s4 = (const float4*)(iybuf + ((((size_t)(b*20+o)*64+nx)*64 + nyt*8)*16));
        ((float4*)dl)[o*32+j] = s4[j];
    }
    if(tid<20){
        float S1 = stat2[(b*20+tid)*2], S2 = stat2[(b*20+tid)*2+1];
        float mean = S1*(1.0f/196608.0f);
        float var = S2*(1.0f/196608.0f) - mean*mean;
        m2l[tid]=mean; s2l[tid]=rsqrtf(var+EPSV);
    }
    for(int t=tid;t<384;t+=256){ czl[t]=tab[768+t]; szl[t]=tab[1152+t]; }
    __syncthreads();
    for(int idx=tid; idx<7680; idx+=256){
        int o = idx/384, p = idx%384;
        int ny = p/48, nz = p%48;
        const float* dd = dl + o*128 + ny*16;
        float acc = dd[0];
        #pragma unroll
        for(int k=1;k<8;k++)
            acc += 2.0f*(dd[k*2]*czl[k*48+nz] - dd[k*2+1]*szl[k*48+nz]);
        float xv = acc*(1.0f/48.0f);
        vl[o*392+p] = (xv - m2l[o])*s2l[o];
    }
    __syncthreads();
    const float* W1 = w1 + li*400;
    const float* W2 = w2 + li*400;
    const float* B1 = b1 + li*20;
    const float* B2 = b2 + li*20;
    for(int p=tid; p<384; p+=256){
        float vj[20], t1[20];
        #pragma unroll
        for(int j2=0;j2<20;j2++) vj[j2]=vl[j2*392+p];
        #pragma unroll
        for(int oo=0;oo<20;oo++){
            float a = B1[oo];
            #pragma unroll
            for(int j2=0;j2<20;j2++) a += vj[j2]*W1[oo*20+j2];
            t1[oo] = geluf(a);
        }
        #pragma unroll
        for(int oo=0;oo<20;oo++){
            float a = B2[oo];
            #pragma unroll
            for(int j2=0;j2<20;j2++) a += t1[j2]*W2[oo*20+j2];
            vl[oo*392+p] = a;
        }
    }
    __syncthreads();
    // phase 4: fused residual (pointwise 1x1 conv over 60 gathered channels) + write
    int sb = (nx*64 + nyt*8)*48;
    if(tid<192){
        const float* W = ww + li*1600;
        float2 acc[20];
        #pragma unroll
        for(int o=0;o<20;o++){ float bv = wb[li*20+o]; acc[o].x=bv; acc[o].y=bv; }
        const float* hb = h + (size_t)(b*80)*SPAT + sb + tid*2;
        for(int c=0;c<20;c++){
            float2 v = *(const float2*)(hb + (size_t)(grp*20+c)*SPAT);
            #pragma unroll
            for(int o=0;o<20;o++){
                float w = W[o*80+c] + W[o*80+20+c];
                acc[o].x += w*v.x; acc[o].y += w*v.y;
            }
        }
        for(int c=0;c<20;c++){
            float2 v = *(const float2*)(hb + (size_t)(g1*20+c)*SPAT);
            #pragma unroll
            for(int o=0;o<20;o++){
                float w = W[o*80+40+c];
                acc[o].x += w*v.x; acc[o].y += w*v.y;
            }
        }
        for(int c=0;c<20;c++){
            float2 v = *(const float2*)(hb + (size_t)(g2*20+c)*SPAT);
            #pragma unroll
            for(int o=0;o<20;o++){
                float w = W[o*80+60+c];
                acc[o].x += w*v.x; acc[o].y += w*v.y;
            }
        }
        #pragma unroll
        for(int o=0;o<20;o++){
            float2 mv = *(const float2*)(vl + o*392 + tid*2);
            float2 r; r.x = mv.x + acc[o].x; r.y = mv.y + acc[o].y;
            *(float2*)(h + (size_t)(b*80+grp*20+o)*SPAT + sb + tid*2) = r;
        }
    }
}

// ---------------- layer-end gelu (in place) ----------------
__global__ void k_gelu(float* __restrict__ h){
    int blk = blockIdx.x;
    size_t base = (size_t)blk*4096;
    float4* hp = (float4*)(h+base);
    for(int e=threadIdx.x;e<1024;e+=blockDim.x){
        float4 v = hp[e];
        v.x=geluf(v.x); v.y=geluf(v.y); v.z=geluf(v.z); v.w=geluf(v.w);
        hp[e]=v;
    }
}

// ---------------- output head: 2 columns/thread, SGPR weights ----------------
__global__ void __launch_bounds__(256) k_head(const float* __restrict__ h,
        const float* __restrict__ qw1, const float* __restrict__ qb1,
        const float* __restrict__ qw2, const float* __restrict__ qb2,
        float* __restrict__ out){
    int g = blockIdx.x & 3;
    int t = (blockIdx.x>>2)*256 + threadIdx.x;   // 0..196607 column-pairs
    if(t >= 196608) return;
    int b = (t>=98304) ? 1 : 0; int col = (t - b*98304)*2;
    const float* hb = h + (size_t)(b*80+g*20)*SPAT + col;
    float2 in20[20];
    #pragma unroll
    for(int j=0;j<20;j++) in20[j] = *(const float2*)(hb + (size_t)j*SPAT);
    float2 o20[20];
    #pragma unroll
    for(int o2=0;o2<20;o2++){ float bv = qb2[g*20+o2]; o20[o2].x=bv; o20[o2].y=bv; }
    for(int o8=0;o8<80;o8++){
        float bv = qb1[g*80+o8];
        float a0 = bv, a1 = bv;
        #pragma unroll
        for(int j=0;j<20;j++){
            float w = qw1[g*1600 + o8*20 + j];
            a0 += in20[j].x*w; a1 += in20[j].y*w;
        }
        a0 = geluf(a0); a1 = geluf(a1);
        #pragma unroll
        for(int o2=0;o2<20;o2++){
            float w = qw2[g*1600 + o2*80 + o8];
            o20[o2].x += a0*w; o20[o2].y += a1*w;
        }
    }
    float* op0 = out + ((size_t)(b*SPAT)+col)*80 + g*20;
    float* op1 = op0 + 80;
    #pragma unroll
    for(int q2=0;q2<5;q2++){
        *(float4*)(op0 + q2*4) = make_float4(o20[q2*4].x,o20[q2*4+1].x,o20[q2*4+2].x,o20[q2*4+3].x);
        *(float4*)(op1 + q2*4) = make_float4(o20[q2*4].y,o20[q2*4+1].y,o20[q2*4+2].y,o20[q2*4+3].y);
    }
}

extern "C" void kernel_launch(void* const* d_in, const int* in_sizes, int n_in,
                              void* d_out, int out_size, void* d_ws, size_t ws_size,
                              hipStream_t stream){
    (void)in_sizes; (void)n_in; (void)out_size;
    const float* x    = (const float*)d_in[0];
    const float* p_w  = (const float*)d_in[1];
    const float* p_b  = (const float*)d_in[2];
    const float* spec = (const float*)d_in[3];
    const float* w1   = (const float*)d_in[4];
    const float* b1   = (const float*)d_in[5];
    const float* w2   = (const float*)d_in[6];
    const float* b2   = (const float*)d_in[7];
    const float* ww   = (const float*)d_in[8];
    const float* wb   = (const float*)d_in[9];
    const float* qw1  = (const float*)d_in[10];
    const float* qb1  = (const float*)d_in[11];
    const float* qw2  = (const float*)d_in[12];
    const float* qb2  = (const float*)d_in[13];
    float* out = (float*)d_out;
    float* ws  = (float*)d_ws;

    if(ws_size < (size_t)37545552*4) return;  // ~150 MB scratch

    float* h      = ws;                       // 31,457,280
    float* ybuf   = ws + 31457280;            //  2,621,440
    float* gbuf   = ws + 34078720;            //    163,840
    float* iyb    = ws + 34242560;            //  2,621,440
    float* fbufC  = ws + 36864000;            //    655,360
    float* partZY = ws + 37519360;            //     20,480
    float* stat2  = ws + 37539840;            //         80
    float* tab    = ws + 37539920;            //      5,632

    k_tables<<<1,256,0,stream>>>(tab);
    k_lift<<<1536,256,0,stream>>>(x, p_w, p_b, h);

    static const int ORD3[4][3] = {{0,1,2},{1,2,3},{2,3,0},{3,0,1}};
    for(int l=0;l<4;l++){
        for(int bi=0;bi<2;bi++){
            if(bi==0){
                k_zy  <<<10240,256,0,stream>>>(h, ybuf, partZY, tab, 0,1,2,3);
                k_xdft<<< 2560,128,0,stream>>>(ybuf, fbufC, partZY, tab, 0,1,2,3);
            } else {
                k_zy  <<< 5120,256,0,stream>>>(h, ybuf, partZY, tab, 0,1,0,0);
                k_xdft<<< 1280,128,0,stream>>>(ybuf, fbufC, partZY, tab, 0,1,0,0);
            }
            for(int ii=0;ii<2;ii++){
                int i = bi*2+ii; int li = l*4+i;
                int g0=ORD3[i][0], g1=ORD3[i][1], g2=ORD3[i][2];
                (void)g0;
                k_spec <<< 320,256,0,stream>>>(fbufC, spec, gbuf, stat2, li, g0,g1,g2);
                k_inv  <<<2560,128,0,stream>>>(gbuf, iyb, stat2, tab);
                k_passD<<<1024,256,0,stream>>>(iyb, w1, b1, w2, b2, ww, wb, h, stat2, tab, li, i, g1, g2);
            }
        }
        if(l<3) k_gelu<<<7680,256,0,stream>>>(h);
    }
    k_head<<<3072,256,0,stream>>>(h, qw1, qb1, qw2, qb2, out);
}

// Round 7
// 3268.760 us; speedup vs baseline: 6.5547x; 1.0339x over previous
//
#include <hip/hip_runtime.h>
#include <math.h>

#define SPAT 196608   // 64*64*48
#define EPSV 1e-5f

// fast gelu: Abramowitz-Stegun 7.1.26 erf approx (abs err <= 1.5e-7)
__device__ __forceinline__ float geluf(float x){
    float ax = fabsf(x)*0.70710678118654752440f;
    float t = __builtin_amdgcn_rcpf(1.0f + 0.3275911f*ax);
    float p = ((((1.061405429f*t - 1.453152027f)*t + 1.421413741f)*t - 0.284496736f)*t + 0.254829592f)*t;
    float e = 1.0f - p*__expf(-ax*ax);
    float er = copysignf(e, x);
    return 0.5f*x*(1.0f + er);
}
__device__ __forceinline__ float wred(float v){
    #pragma unroll
    for(int o=32;o>0;o>>=1) v += __shfl_down(v,o);
    return v;
}

// ---------------- twiddle tables ----------------
// 768:  czT [k*48+z]   384   (k_zy fwd z-DFT via SGPR, passD z-inverse)
// 1152: szT [k*48+z]   384
// 1536: cxy [y*16+ki]  1024  (k_inv)
// 2560: sxy [y*16+ki]  1024
// 3584: cxyT[ki*64+y]  1024  (k_zy y-stage / k_xdft forward)
// 4608: sxyT[ki*64+y]  1024
__global__ void k_tables(float* tab){
    for(int idx=threadIdx.x; idx<384; idx+=blockDim.x){
        int z = idx>>3, k = idx&7;
        double a = 6.283185307179586476925286766559 * (double)((k*z)%48) / 48.0;
        float c = (float)cos(a), s = (float)sin(a);
        tab[idx]=c; tab[384+idx]=s;
        tab[768 + k*48+z]=c; tab[1152 + k*48+z]=s;
    }
    for(int idx=threadIdx.x; idx<1024; idx+=blockDim.x){
        int y = idx>>4, ki = idx&15;
        int ka = ki<8 ? ki : ki+48;
        double a = 6.283185307179586476925286766559 * (double)((ka*y)%64) / 64.0;
        float c=(float)cos(a), s=(float)sin(a);
        tab[1536+idx]=c; tab[2560+idx]=s;
        tab[3584 + ki*64+y]=c; tab[4608 + ki*64+y]=s;
    }
}

// ---------------- lifting: global-direct, SGPR weights ----------------
__global__ void __launch_bounds__(256) k_lift(const float* __restrict__ x,
                       const float* __restrict__ pw, const float* __restrict__ pb,
                       float* __restrict__ h){
    int t = blockIdx.x*256 + threadIdx.x;      // 393216 total
    int b = (t>=SPAT) ? 1 : 0; int col = t - b*SPAT;
    int xy = col/48, z = col%48;
    const float4* xp = (const float4*)(x + (size_t)t*40);
    float in[40];
    #pragma unroll
    for(int q=0;q<10;q++){
        float4 v = xp[q];
        in[q*4]=v.x; in[q*4+1]=v.y; in[q*4+2]=v.z; in[q*4+3]=v.w;
    }
    float gx = (float)(xy>>6)*(1.0f/63.0f);
    float gy = (float)(xy&63)*(1.0f/63.0f);
    float gz = (float)z*(1.0f/47.0f);
    for(int g=0;g<4;g++){
        const float* w = pw + g*260;
        #pragma unroll 4
        for(int c=0;c<20;c++){
            float a = pb[g*20+c];
            #pragma unroll
            for(int j=0;j<10;j++) a += in[g*10+j]*w[j*20+c];
            a += gx*w[200+c] + gy*w[220+c] + gz*w[240+c];
            h[(size_t)(b*80+g*20+c)*SPAT + col] = a;
        }
    }
}

// ---------------- fused forward z+y DFT + stats partials (+ lazy gelu) ----------------
// register z-partial DFT with SGPR twiddles; no staging LDS, no bank conflicts
__global__ void __launch_bounds__(256) k_zy(const float* __restrict__ h,
        float* __restrict__ ybuf, float* __restrict__ partZY,
        const float* __restrict__ tab, int gA,int gB,int gC,int gD, int gflag){
    __shared__ float sp4[4*16*65];              // [q4][k*2+ri][y] stride 65
    __shared__ float cyl[16*65], syl[16*65];    // [ky][y] stride 65
    __shared__ float sred[8];
    int blk = blockIdx.x;
    int x = blk&63; int d=(blk>>6)%20; int r2 = blk/1280; int b = r2&1; int gi = r2>>1;
    int gl4[4]={gA,gB,gC,gD};
    int g = gl4[gi];
    int ch = g*20+d;
    int tid=threadIdx.x;
    int y = tid&63, q4 = tid>>6;   // q4 wave-uniform
    const float4* src = (const float4*)(h + (size_t)(b*80+ch)*SPAT + (size_t)x*3072
                                          + (size_t)(y*48 + q4*12));
    float v[12];
    #pragma unroll
    for(int u=0;u<3;u++){
        float4 t4 = src[u];
        v[u*4]=t4.x; v[u*4+1]=t4.y; v[u*4+2]=t4.z; v[u*4+3]=t4.w;
    }
    if(gflag){
        #pragma unroll
        for(int j=0;j<12;j++) v[j]=geluf(v[j]);
    }
    float s1=0,s2=0;
    #pragma unroll
    for(int j=0;j<12;j++){ s1+=v[j]; s2+=v[j]*v[j]; }
    for(int tt=tid;tt<1024;tt+=256){
        int ki=tt>>6, yy=tt&63;
        cyl[ki*65+yy]=tab[3584+tt]; syl[ki*65+yy]=tab[4608+tt];
    }
    // z partial DFT: twiddles wave-uniform (q4, k, j) -> s_load
    const float* CZ = tab+768  + q4*12;
    const float* SZ = tab+1152 + q4*12;
    #pragma unroll
    for(int k=0;k<8;k++){
        float rr=0, si=0;
        #pragma unroll
        for(int j=0;j<12;j++){ rr += v[j]*CZ[k*48+j]; si += v[j]*SZ[k*48+j]; }
        sp4[(q4*16 + k*2)*65 + y]   = rr;
        sp4[(q4*16 + k*2+1)*65 + y] = -si;
    }
    s1=wred(s1); s2=wred(s2);
    if((tid&63)==0){ sred[(tid>>6)*2]=s1; sred[(tid>>6)*2+1]=s2; }
    __syncthreads();
    if(tid==0){
        size_t pi = ((size_t)(b*80+ch)*64+x)*2;
        partZY[pi]   = sred[0]+sred[2]+sred[4]+sred[6];
        partZY[pi+1] = sred[1]+sred[3]+sred[5]+sred[7];
    }
    // combine 4 partials in place (each entry owned by exactly one thread)
    #pragma unroll
    for(int j=0;j<4;j++){
        int e = tid + j*256;
        int kri = e>>6, yy = e&63;
        float sum = sp4[kri*65+yy] + sp4[(16+kri)*65+yy]
                  + sp4[(32+kri)*65+yy] + sp4[(48+kri)*65+yy];
        sp4[kri*65+yy] = sum;
    }
    __syncthreads();
    // y-DFT: 128 tasks (ky,kz); same-address reads broadcast
    if(tid<128){
        int ky=tid>>3, kz=tid&7;
        const float* cy = cyl+ky*65; const float* sy = syl+ky*65;
        const float* spr = sp4 + (kz*2)*65;
        const float* spi = sp4 + (kz*2+1)*65;
        float fr=0, fi=0;
        #pragma unroll 8
        for(int yy=0;yy<64;yy++){
            float sr=spr[yy], si=spi[yy];
            float c=cy[yy], s=sy[yy];
            fr += sr*c + si*s;
            fi += si*c - sr*s;
        }
        size_t base = ((size_t)((g*2+b)*20+d)*16 + ky)*1024 + (size_t)(kz*128);
        ybuf[base + x]      = fr;
        ybuf[base + 64 + x] = fi;
    }
}

// ---------------- forward x-DFT + norm1 fold -> per-channel cache ----------------
__global__ void __launch_bounds__(128) k_xdft(const float* __restrict__ ybuf,
        float* __restrict__ fbufC, const float* __restrict__ partZY,
        const float* __restrict__ tab, int gA,int gB,int gC,int gD){
    __shared__ __align__(16) float ylx[16*68];  // [kz*2+ri][x] stride 68
    __shared__ float cxl[16*65], sxl[16*65];
    __shared__ float scs[1];
    int blk = blockIdx.x;
    int kyi = blk&15; int d=(blk>>4)%20; int r2=blk/320; int b=r2&1; int gi=r2>>1;
    int gl4[4]={gA,gB,gC,gD};
    int g=gl4[gi]; int ch=g*20+d;
    int tid=threadIdx.x;
    const float4* src = (const float4*)(ybuf + (((size_t)((g*2+b)*20+d)*16+kyi)*1024));
    #pragma unroll
    for(int u=0;u<2;u++){
        int e=tid+u*128; float4 v=src[e];
        int kzri = e>>4; int xx=(e&15)*4;
        *(float4*)(ylx + kzri*68 + xx) = v;
    }
    for(int tt=tid;tt<1024;tt+=128){
        int ki=tt>>6, y=tt&63;
        cxl[ki*65+y]=tab[3584+tt]; sxl[ki*65+y]=tab[4608+tt];
    }
    float s1=0,s2=0;
    if(tid<64){
        size_t pi=((size_t)(b*80+ch)*64+tid)*2;
        s1=partZY[pi]; s2=partZY[pi+1];
    }
    s1=wred(s1); s2=wred(s2);
    if(tid==0){
        float mean=s1*(1.0f/196608.0f);
        float var=s2*(1.0f/196608.0f)-mean*mean;
        scs[0]=rsqrtf(var+EPSV);
    }
    __syncthreads();
    float sc = scs[0];
    int kxi=tid>>3, kz=tid&7;
    const float* yr = ylx + (kz*2)*68;
    const float* yi = ylx + (kz*2+1)*68;
    const float* cx = cxl + kxi*65;
    const float* sx = sxl + kxi*65;
    float fr=0, fi=0;
    #pragma unroll 8
    for(int xx=0;xx<64;xx++){
        float a=yr[xx], e2=yi[xx];
        float c=cx[xx], s=sx[xx];
        fr += a*c + e2*s;
        fi += e2*c - a*s;
    }
    fr*=sc; fi*=sc;
    if(kxi==0 && kyi==0 && kz==0){ fr=0.0f; fi=0.0f; }
    size_t idx = ((size_t)(b*80+ch)*2048 + (size_t)((kxi*16+kyi)*8+kz))*2;
    fbufC[idx]=fr; fbufC[idx+1]=fi;
}

// ---------------- spectral multiply: 256 threads, 4-way c-split ----------------
__global__ void __launch_bounds__(256) k_spec(const float* __restrict__ fbufC,
        const float* __restrict__ sw, float* __restrict__ gbuf,
        float* __restrict__ stat2, int li, int g0, int g1, int g2){
    __shared__ float part[2112];
    int blk = blockIdx.x;
    int m1p = blk & 3, o = (blk>>2)%20, q = blk/80;
    int tid = threadIdx.x;
    int t64 = tid & 63, cc = tid >> 6;
    if(q==0 && m1p==0 && tid<2){
        stat2[(tid*20+o)*2]=0.f; stat2[(tid*20+o)*2+1]=0.f;
    }
    int offx = (q&1)*8, offy = (q>>1)*8;
    int m1 = m1p*2 + (t64>>5);
    int m2 = (t64>>2)&7;
    int m3 = (t64&3)*2;
    int tw = m1*64 + m2*8 + m3;
    int kxi = m1+offx, kyi = m2+offy;
    int fo = (kxi*16 + kyi)*8 + m3;   // even
    const float4* wp = (const float4*)(sw + (((size_t)(li*4+q)*1600) + o)*1024 + (size_t)tw*2);
    const float4* fb = (const float4*)fbufC + (fo>>1);
    float r00=0,i00=0,r01=0,i01=0, r10=0,i10=0,r11=0,i11=0;
    int c0 = cc*5;
    #pragma unroll
    for(int u=0;u<5;u++){
        int c = c0+u;
        float4 wa = wp[(size_t)c*5120];
        float4 wb4= wp[(size_t)(c+20)*5120];
        float wr0 = wa.x + wb4.x, wi0 = wa.y + wb4.y, wr1 = wa.z + wb4.z, wi1 = wa.w + wb4.w;
        float4 f0 = fb[(size_t)(g0*20+c)*1024];
        float4 f1 = fb[(size_t)(80+g0*20+c)*1024];
        r00 += f0.x*wr0 - f0.y*wi0; i00 += f0.x*wi0 + f0.y*wr0;
        r01 += f0.z*wr1 - f0.w*wi1; i01 += f0.z*wi1 + f0.w*wr1;
        r10 += f1.x*wr0 - f1.y*wi0; i10 += f1.x*wi0 + f1.y*wr0;
        r11 += f1.z*wr1 - f1.w*wi1; i11 += f1.z*wi1 + f1.w*wr1;
    }
    #pragma unroll
    for(int u=0;u<5;u++){
        int c = c0+u;
        float4 wa = wp[(size_t)(c+40)*5120];
        float4 f0 = fb[(size_t)(g1*20+c)*1024];
        float4 f1 = fb[(size_t)(80+g1*20+c)*1024];
        r00 += f0.x*wa.x - f0.y*wa.y; i00 += f0.x*wa.y + f0.y*wa.x;
        r01 += f0.z*wa.z - f0.w*wa.w; i01 += f0.z*wa.w + f0.w*wa.z;
        r10 += f1.x*wa.x - f1.y*wa.y; i10 += f1.x*wa.y + f1.y*wa.x;
        r11 += f1.z*wa.z - f1.w*wa.w; i11 += f1.z*wa.w + f1.w*wa.z;
    }
    #pragma unroll
    for(int u=0;u<5;u++){
        int c = c0+u;
        float4 wa = wp[(size_t)(c+60)*5120];
        float4 f0 = fb[(size_t)(g2*20+c)*1024];
        float4 f1 = fb[(size_t)(80+g2*20+c)*1024];
        r00 += f0.x*wa.x - f0.y*wa.y; i00 += f0.x*wa.y + f0.y*wa.x;
        r01 += f0.z*wa.z - f0.w*wa.w; i01 += f0.z*wa.w + f0.w*wa.z;
        r10 += f1.x*wa.x - f1.y*wa.y; i10 += f1.x*wa.y + f1.y*wa.x;
        r11 += f1.z*wa.z - f1.w*wa.w; i11 += f1.z*wa.w + f1.w*wa.z;
    }
    float vals[8]={r00,i00,r01,i01,r10,i10,r11,i11};
    #pragma unroll
    for(int e=0;e<8;e++) part[t64*33 + e*4 + cc] = vals[e];
    __syncthreads();
    if(cc==0){
        float acc[8];
        #pragma unroll
        for(int e=0;e<8;e++){
            const float* p = part + t64*33 + e*4;
            acc[e] = p[0]+p[1]+p[2]+p[3];
        }
        float4* gg0 = (float4*)(gbuf + (size_t)o*4096 + fo*2);
        float4* gg1 = (float4*)(gbuf + (size_t)(20+o)*4096 + fo*2);
        *gg0 = make_float4(acc[0],acc[1],acc[2],acc[3]);
        *gg1 = make_float4(acc[4],acc[5],acc[6],acc[7]);
    }
}

// ---------------- fused inverse x + y (+ Parseval stats for norm2) ----------------
__global__ void k_inv(const float* __restrict__ gbuf, float* __restrict__ iybuf,
                      float* __restrict__ stat2, const float* __restrict__ tab){
    __shared__ __align__(16) float gl[4096];
    __shared__ float tmp[256];
    __shared__ float cl[1088], sl[1088];   // [y][ki] stride 17
    __shared__ float ig[4];
    int blk = blockIdx.x;
    int nx = blk&63, o = (blk>>6)%20, b = blk/1280;
    const float4* src4 = (const float4*)(gbuf + (size_t)(b*20+o)*4096);
    for(int t=threadIdx.x;t<1024;t+=blockDim.x) ((float4*)gl)[t]=src4[t];
    for(int t=threadIdx.x;t<1024;t+=blockDim.x){
        int y=t>>4, ki=t&15;
        cl[y*17+ki]=tab[1536+t]; sl[y*17+ki]=tab[2560+t];
    }
    __syncthreads();
    {
        int kyi = threadIdx.x>>3, kz = threadIdx.x&7;
        float ar=0, ai=0;
        #pragma unroll 4
        for(int kxi=0;kxi<16;kxi++){
            float gr = gl[((kxi*16+kyi)*8+kz)*2], gi2 = gl[((kxi*16+kyi)*8+kz)*2+1];
            float c = cl[nx*17+kxi], s = sl[nx*17+kxi];
            ar += gr*c - gi2*s;
            ai += gi2*c + gr*s;
        }
        tmp[threadIdx.x*2]   = ar*(1.0f/64.0f);
        tmp[threadIdx.x*2+1] = ai*(1.0f/64.0f);
    }
    __syncthreads();
    float p1=0,p2=0;
    for(int j=0;j<4;j++){
        int out = threadIdx.x + j*128;
        int ny = out>>3, kz = out&7;
        float ar=0, ai=0;
        #pragma unroll 4
        for(int kyi=0;kyi<16;kyi++){
            float vr = tmp[(kyi*8+kz)*2], vi = tmp[(kyi*8+kz)*2+1];
            float c = cl[ny*17+kyi], s = sl[ny*17+kyi];
            ar += vr*c - vi*s;
            ai += vi*c + vr*s;
        }
        ar *= (1.0f/64.0f); ai *= (1.0f/64.0f);
        size_t idx = ((((size_t)(b*20+o)*64+nx)*64+ny)*8+kz)*2;
        iybuf[idx]=ar; iybuf[idx+1]=ai;
        if(kz==0){ p1 += ar; p2 += ar*ar; }
        else p2 += 2.0f*(ar*ar+ai*ai);
    }
    p2 *= (1.0f/48.0f);
    float r1=wred(p1), r2=wred(p2);
    int wv = threadIdx.x>>6;
    if((threadIdx.x&63)==0){ ig[wv*2]=r1; ig[wv*2+1]=r2; }
    __syncthreads();
    if(threadIdx.x==0){
        atomicAdd(&stat2[(b*20+o)*2],   ig[0]+ig[2]);
        atomicAdd(&stat2[(b*20+o)*2+1], ig[1]+ig[3]);
    }
}

// ---------------- pass D: z-inverse + norm2 + MLP + residual(+lazy gelu) + h write ----------------
// single-pass per column-pair, all state in registers (fully unrolled)
__global__ void __launch_bounds__(256) k_passD(
        const float* __restrict__ iybuf,
        const float* __restrict__ w1, const float* __restrict__ b1,
        const float* __restrict__ w2, const float* __restrict__ b2,
        const float* __restrict__ ww, const float* __restrict__ wb,
        float* __restrict__ h,
        const float* __restrict__ stat2, const float* __restrict__ tab,
        int li, int grp, int g1, int g2, int f0, int f1, int f2){
    __shared__ __align__(16) float dl[2560];
    __shared__ float m2l[20], s2l[20];
    __shared__ float czl[384], szl[384];   // [k][z]
    int blk = blockIdx.x;
    int nyt = blk&7, nx=(blk>>3)&63, b = blk>>9;
    int tid = threadIdx.x;
    for(int u=tid; u<640; u+=256){
        int o = u>>5, j = u&31;
        const float4* s4 = (const float4*)(iybuf + ((((size_t)(b*20+o)*64+nx)*64 + nyt*8)*16));
        ((float4*)dl)[o*32+j] = s4[j];
    }
    if(tid<20){
        float S1 = stat2[(b*20+tid)*2], S2 = stat2[(b*20+tid)*2+1];
        float mean = S1*(1.0f/196608.0f);
        float var = S2*(1.0f/196608.0f) - mean*mean;
        m2l[tid]=mean; s2l[tid]=rsqrtf(var+EPSV);
    }
    for(int t=tid;t<384;t+=256){ czl[t]=tab[768+t]; szl[t]=tab[1152+t]; }
    __syncthreads();
    if(tid>=192) return;
    int p0 = tid*2;                       // columns p0, p0+1 (same ny always)
    int nyl = p0/48, nz0 = p0 - nyl*48;
    // z-inverse + norm2 -> registers
    float vj0[20], vj1[20];
    #pragma unroll
    for(int o=0;o<20;o++){
        const float* dd = dl + o*128 + nyl*16;
        float a0 = dd[0], a1 = dd[0];
        #pragma unroll
        for(int k=1;k<8;k++){
            float dr = dd[k*2], di = dd[k*2+1];
            a0 += 2.0f*(dr*czl[k*48+nz0]   - di*szl[k*48+nz0]);
            a1 += 2.0f*(dr*czl[k*48+nz0+1] - di*szl[k*48+nz0+1]);
        }
        vj0[o] = (a0*(1.0f/48.0f) - m2l[o])*s2l[o];
        vj1[o] = (a1*(1.0f/48.0f) - m2l[o])*s2l[o];
    }
    // MLP (scalar weights)
    const float* W1 = w1 + li*400; const float* W2 = w2 + li*400;
    const float* B1 = b1 + li*20;  const float* B2 = b2 + li*20;
    float t10[20], t11[20];
    #pragma unroll
    for(int oo=0;oo<20;oo++){
        float a0=B1[oo], a1=a0;
        #pragma unroll
        for(int j=0;j<20;j++){ float w=W1[oo*20+j]; a0+=vj0[j]*w; a1+=vj1[j]*w; }
        t10[oo]=geluf(a0); t11[oo]=geluf(a1);
    }
    float o0[20], o1[20];
    #pragma unroll
    for(int oo=0;oo<20;oo++){
        float a0=B2[oo], a1=a0;
        #pragma unroll
        for(int j=0;j<20;j++){ float w=W2[oo*20+j]; a0+=t10[j]*w; a1+=t11[j]*w; }
        o0[oo]=a0; o1[oo]=a1;
    }
    // fused residual conv over 60 channels, lazy gelu per slot flags
    int sb = (nx*64 + nyt*8)*48;
    const float* W = ww + li*1600;
    const float* hb = h + (size_t)(b*80)*SPAT + sb + p0;
    #pragma unroll
    for(int o=0;o<20;o++){ float bv=wb[li*20+o]; o0[o]+=bv; o1[o]+=bv; }
    for(int c=0;c<20;c++){
        float2 vv = *(const float2*)(hb + (size_t)(grp*20+c)*SPAT);
        if(f0){ vv.x=geluf(vv.x); vv.y=geluf(vv.y); }
        #pragma unroll
        for(int o=0;o<20;o++){
            float w = W[o*80+c] + W[o*80+20+c];
            o0[o]+=w*vv.x; o1[o]+=w*vv.y;
        }
    }
    for(int c=0;c<20;c++){
        float2 vv = *(const float2*)(hb + (size_t)(g1*20+c)*SPAT);
        if(f1){ vv.x=geluf(vv.x); vv.y=geluf(vv.y); }
        #pragma unroll
        for(int o=0;o<20;o++){
            float w = W[o*80+40+c];
            o0[o]+=w*vv.x; o1[o]+=w*vv.y;
        }
    }
    for(int c=0;c<20;c++){
        float2 vv = *(const float2*)(hb + (size_t)(g2*20+c)*SPAT);
        if(f2){ vv.x=geluf(vv.x); vv.y=geluf(vv.y); }
        #pragma unroll
        for(int o=0;o<20;o++){
            float w = W[o*80+60+c];
            o0[o]+=w*vv.x; o1[o]+=w*vv.y;
        }
    }
    #pragma unroll
    for(int o=0;o<20;o++)
        *(float2*)(h + (size_t)(b*80+grp*20+o)*SPAT + sb + p0) = make_float2(o0[o],o1[o]);
}

// ---------------- output head: 2 columns/thread, SGPR weights ----------------
__global__ void __launch_bounds__(256) k_head(const float* __restrict__ h,
        const float* __restrict__ qw1, const float* __restrict__ qb1,
        const float* __restrict__ qw2, const float* __restrict__ qb2,
        float* __restrict__ out){
    int g = blockIdx.x & 3;
    int t = (blockIdx.x>>2)*256 + threadIdx.x;   // 0..196607 column-pairs
    if(t >= 196608) return;
    int b = (t>=98304) ? 1 : 0; int col = (t - b*98304)*2;
    const float* hb = h + (size_t)(b*80+g*20)*SPAT + col;
    float2 in20[20];
    #pragma unroll
    for(int j=0;j<20;j++) in20[j] = *(const float2*)(hb + (size_t)j*SPAT);
    float2 o20[20];
    #pragma unroll
    for(int o2=0;o2<20;o2++){ float bv = qb2[g*20+o2]; o20[o2].x=bv; o20[o2].y=bv; }
    for(int o8=0;o8<80;o8++){
        float bv = qb1[g*80+o8];
        float a0 = bv, a1 = bv;
        #pragma unroll
        for(int j=0;j<20;j++){
            float w = qw1[g*1600 + o8*20 + j];
            a0 += in20[j].x*w; a1 += in20[j].y*w;
        }
        a0 = geluf(a0); a1 = geluf(a1);
        #pragma unroll
        for(int o2=0;o2<20;o2++){
            float w = qw2[g*1600 + o2*80 + o8];
            o20[o2].x += a0*w; o20[o2].y += a1*w;
        }
    }
    float* op0 = out + ((size_t)(b*SPAT)+col)*80 + g*20;
    float* op1 = op0 + 80;
    #pragma unroll
    for(int q2=0;q2<5;q2++){
        *(float4*)(op0 + q2*4) = make_float4(o20[q2*4].x,o20[q2*4+1].x,o20[q2*4+2].x,o20[q2*4+3].x);
        *(float4*)(op1 + q2*4) = make_float4(o20[q2*4].y,o20[q2*4+1].y,o20[q2*4+2].y,o20[q2*4+3].y);
    }
}

extern "C" void kernel_launch(void* const* d_in, const int* in_sizes, int n_in,
                              void* d_out, int out_size, void* d_ws, size_t ws_size,
                              hipStream_t stream){
    (void)in_sizes; (void)n_in; (void)out_size;
    const float* x    = (const float*)d_in[0];
    const float* p_w  = (const float*)d_in[1];
    const float* p_b  = (const float*)d_in[2];
    const float* spec = (const float*)d_in[3];
    const float* w1   = (const float*)d_in[4];
    const float* b1   = (const float*)d_in[5];
    const float* w2   = (const float*)d_in[6];
    const float* b2   = (const float*)d_in[7];
    const float* ww   = (const float*)d_in[8];
    const float* wb   = (const float*)d_in[9];
    const float* qw1  = (const float*)d_in[10];
    const float* qb1  = (const float*)d_in[11];
    const float* qw2  = (const float*)d_in[12];
    const float* qb2  = (const float*)d_in[13];
    float* out = (float*)d_out;
    float* ws  = (float*)d_ws;

    if(ws_size < (size_t)37545552*4) return;  // ~150 MB scratch

    float* h      = ws;                       // 31,457,280
    float* ybuf   = ws + 31457280;            //  2,621,440
    float* gbuf   = ws + 34078720;            //    163,840
    float* iyb    = ws + 34242560;            //  2,621,440
    float* fbufC  = ws + 36864000;            //    655,360
    float* partZY = ws + 37519360;            //     20,480
    float* stat2  = ws + 37539840;            //         80
    float* tab    = ws + 37539920;            //      5,632

    k_tables<<<1,256,0,stream>>>(tab);
    k_lift<<<1536,256,0,stream>>>(x, p_w, p_b, h);

    static const int ORD3[4][3] = {{0,1,2},{1,2,3},{2,3,0},{3,0,1}};
    for(int l=0;l<4;l++){
        int lf = (l>0)?1:0;
        for(int bi=0;bi<2;bi++){
            if(bi==0){
                // all 4 groups, pre-layer h (raw -> lazy gelu if l>0)
                k_zy  <<<10240,256,0,stream>>>(h, ybuf, partZY, tab, 0,1,2,3, lf);
                k_xdft<<< 2560,128,0,stream>>>(ybuf, fbufC, partZY, tab, 0,1,2,3);
            } else {
                // groups 0,1 freshly updated this layer -> no gelu
                k_zy  <<< 5120,256,0,stream>>>(h, ybuf, partZY, tab, 0,1,0,0, 0);
                k_xdft<<< 1280,128,0,stream>>>(ybuf, fbufC, partZY, tab, 0,1,0,0);
            }
            for(int ii=0;ii<2;ii++){
                int i = bi*2+ii; int li = l*4+i;
                int g0=ORD3[i][0], g1=ORD3[i][1], g2=ORD3[i][2];
                (void)g0;
                int f0 = lf;                      // grp not yet updated this layer
                int f1 = (g1<i)?0:lf;             // gelu iff not updated this layer
                int f2 = (g2<i)?0:lf;
                k_spec <<< 320,256,0,stream>>>(fbufC, spec, gbuf, stat2, li, i, g1, g2);
                k_inv  <<<2560,128,0,stream>>>(gbuf, iyb, stat2, tab);
                k_passD<<<1024,256,0,stream>>>(iyb, w1, b1, w2, b2, ww, wb, h, stat2, tab,
                                               li, i, g1, g2, f0, f1, f2);
            }
        }
    }
    k_head<<<3072,256,0,stream>>>(h, qw1, qb1, qw2, qb2, out);
}